// Round 6
// baseline (2205.128 us; speedup 1.0000x reference)
//
#include <hip/hip_runtime.h>
#include <hip/hip_bf16.h>

typedef _Float16 f16;
typedef _Float16 f16x8 __attribute__((ext_vector_type(8)));
typedef _Float16 h2 __attribute__((ext_vector_type(2)));
typedef float f32x4 __attribute__((ext_vector_type(4)));
typedef unsigned ui4v __attribute__((ext_vector_type(4)));
typedef unsigned long long ull;

#define B_ 8
#define S_ 512
#define H_ 768
#define V_ 35004
#define J_ 30
#define K_ 9
#define R_ 2160          // B*J*K rows, row r = b*270 + j*9 + t  (matches out layout)
#define H3 2304

// ---------------------------------------------------------------- prep kernels

__global__ void k_zero(int* p, int n) {
    int i = blockIdx.x * 256 + threadIdx.x;
    if (i < n) p[i] = 0;
}

__global__ void k_cast(const float* __restrict__ s, f16* __restrict__ d, long n) {
    for (long i = (long)blockIdx.x * 256 + threadIdx.x; i < n; i += (long)gridDim.x * 256)
        d[i] = (f16)s[i];
}

// W_all[r] = (t==0) ? decoder_input[b,j,:] : embed[teacher[b,j,t-1],:]
__global__ void k_build_wall(const float* __restrict__ emb, const float* __restrict__ dec,
                             const int* __restrict__ teacher, f16* __restrict__ Wall) {
    int r = blockIdx.x;
    int b = r / 270, s = r % 270, j = s / 9, t = s % 9;
    const float* src = (t == 0) ? dec + ((long)b * J_ + j) * H_
                                : emb + (long)teacher[((long)b * J_ + j) * K_ + (t - 1)] * H_;
    f16* dst = Wall + (long)r * H_;
    for (int c = threadIdx.x; c < H_; c += 256) dst[c] = (f16)src[c];
}

// enc hi/lo split (row-major [b][s][h]) + encT hi ([b][h][s]) for context GEMM
__global__ void k_build_enc(const float* __restrict__ enc, f16* __restrict__ ehi,
                            f16* __restrict__ elo, f16* __restrict__ encT) {
    long n = (long)B_ * S_ * H_;
    for (long i = (long)blockIdx.x * 256 + threadIdx.x; i < n; i += (long)gridDim.x * 256) {
        float v = enc[i];
        f16 hi = (f16)v;
        ehi[i] = hi;
        elo[i] = (f16)(v - (float)hi);
        int h = (int)(i % H_);
        long bs = i / H_;
        int s = (int)(bs % S_), b = (int)(bs / S_);
        encT[((long)b * H_ + h) * S_ + s] = hi;
    }
}

// h exchange word {seq:32 | f32:32}; write both the L2 copy and the MALL mirror.
__global__ void k_init_h(const float* __restrict__ hidden, ull* __restrict__ hL,
                         ull* __restrict__ hM) {
    int i = blockIdx.x * 256 + threadIdx.x;
    if (i < B_ * H_) {
        int b = i / H_, u = i % H_;
        ull w = (ull)__float_as_uint(hidden[i]);  // seq 0
        hL[(long)b * 1536 + u] = w;
        hM[(long)b * 1536 + u] = w;
    }
}

// ---------------------------------------------------------------- f16 MFMA GEMM
// C[M,N] = A[M,K] @ B[N,K]^T ; MODE 0: store, 1: store + bias[col], 2: C += result
template <int MODE>
__global__ __launch_bounds__(256) void k_gemm(const f16* __restrict__ A, const f16* __restrict__ Bm,
                                              float* __restrict__ C, const float* __restrict__ bias,
                                              int M, int N, int K, long sA, long sB, long sC) {
    A += (long)blockIdx.z * sA;
    Bm += (long)blockIdx.z * sB;
    C += (long)blockIdx.z * sC;
    const int m0 = blockIdx.y * 128, n0 = blockIdx.x * 128;
    __shared__ f16 As[128][56];   // stride 56 f16 = 112B: 16B-aligned, bank-spread
    __shared__ f16 Bs[128][56];
    const int tid = threadIdx.x, lane = tid & 63, wave = tid >> 6;
    const int wm = wave >> 1, wn = wave & 1;
    const int fr = lane & 15, kg = lane >> 4;
    f32x4 acc[4][4] = {};
    const int srow = tid >> 2, scol = (tid & 3) * 8;
    for (int kt = 0; kt < K; kt += 32) {
#pragma unroll
        for (int hh = 0; hh < 2; ++hh) {
            int r = srow + hh * 64;
            f16x8 va = {};
            int gr = m0 + r;
            if (gr < M) va = *(const f16x8*)(A + (long)gr * K + kt + scol);
            *(f16x8*)(&As[r][scol]) = va;
            f16x8 vb = {};
            int gc = n0 + r;
            if (gc < N) vb = *(const f16x8*)(Bm + (long)gc * K + kt + scol);
            *(f16x8*)(&Bs[r][scol]) = vb;
        }
        __syncthreads();
        f16x8 af[4], bf[4];
#pragma unroll
        for (int m = 0; m < 4; ++m) af[m] = *(const f16x8*)(&As[wm * 64 + m * 16 + fr][kg * 8]);
#pragma unroll
        for (int n = 0; n < 4; ++n) bf[n] = *(const f16x8*)(&Bs[wn * 64 + n * 16 + fr][kg * 8]);
#pragma unroll
        for (int m = 0; m < 4; ++m)
#pragma unroll
            for (int n = 0; n < 4; ++n)
                acc[m][n] = __builtin_amdgcn_mfma_f32_16x16x32_f16(af[m], bf[n], acc[m][n], 0, 0, 0);
        __syncthreads();
    }
    const int crow = m0 + wm * 64 + (lane >> 4) * 4;
    const int ccol = n0 + wn * 64 + fr;
#pragma unroll
    for (int n = 0; n < 4; ++n) {
        int col = ccol + n * 16;
        if (col >= N) continue;
        float bv = (MODE == 1) ? bias[col] : 0.f;
#pragma unroll
        for (int m = 0; m < 4; ++m) {
#pragma unroll
            for (int q = 0; q < 4; ++q) {
                int row = crow + m * 16 + q;
                if (row < M) {
                    long idx = (long)row * N + col;
                    float v = acc[m][n][q] + bv;
                    if (MODE == 2) v += C[idx];
                    C[idx] = v;
                }
            }
        }
    }
}

// ---------------------------------------------------------------- GRU recurrence
// 256 blocks, 1/CU (LDS-pinned). Each block reads its physical XCD (XCC_ID) and
// joins that XCD's chain: batch = xcd, 24 slices x 32 units (extra blocks exit).
// Weights: f16 in REGISTERS (144 VGPR). h exchange: seq-tagged ull, plain stores
// + sc0 loads within the shared XCD L2; bounded poll falls back to a MALL mirror
// (relaxed agent atomics) so wrong placement degrades to R5 speed, never hangs.
__device__ __forceinline__ float fd2(unsigned hv, unsigned wv, float acc) {
#if __has_builtin(__builtin_amdgcn_fdot2)
    return __builtin_amdgcn_fdot2(__builtin_bit_cast(h2, hv), __builtin_bit_cast(h2, wv), acc, false);
#else
    h2 a = __builtin_bit_cast(h2, hv), b = __builtin_bit_cast(h2, wv);
    return acc + (float)a.x * (float)b.x + (float)a.y * (float)b.y;
#endif
}

__global__ __launch_bounds__(256, 1) void k_gru(const float* __restrict__ gi,
                                                const f16* __restrict__ wh16,
                                                const float* __restrict__ bhh,
                                                ull* hL, ull* hM,
                                                f16* __restrict__ Hhi, f16* __restrict__ Hlo,
                                                int* roster) {
    __shared__ ui4v wsvu[9216];               // 147456B staging; ALSO pins 1 block/CU
    __shared__ __align__(16) f16 hsf[768];
    __shared__ float hs32[768];
    __shared__ float part[8][32][3];
    __shared__ int tick_s;
    const int tid = threadIdx.x;
    unsigned xcc;
    asm("s_getreg_b32 %0, hwreg(HW_REG_XCC_ID)" : "=s"(xcc));
    const int chain = (int)(xcc & 7);
    if (tid == 0) tick_s = atomicAdd(roster + chain, 1);
    __syncthreads();
    const int slice = tick_s;
    if (slice >= 24) return;
    const int u0 = slice * 32;
    // stage weight slice to LDS (coalesced), then lift into registers
    for (int idx = tid; idx < 9216; idx += 256) {
        int u = idx & 31, k8 = (idx >> 5) % 96, g = idx / (96 * 32);
        wsvu[idx] = *(const ui4v*)(wh16 + (long)(g * H_ + u0 + u) * H_ + k8 * 8);
    }
    float b_r = 0.f, b_z = 0.f, b_n = 0.f;
    if (tid < 32) {
        int c = u0 + tid;
        b_r = bhh[c];
        b_z = bhh[H_ + c];
        b_n = bhh[2 * H_ + c];
    }
    __syncthreads();
    const int u = tid & 31, q = tid >> 5;
    ui4v wreg[3][12];
#pragma unroll
    for (int g = 0; g < 3; ++g)
#pragma unroll
        for (int i = 0; i < 12; ++i)
            wreg[g][i] = wsvu[(g * 96 + q * 12 + i) * 32 + u];

    ull* baseL = hL + (long)chain * 1536;
    ull* baseM = hM + (long)chain * 1536;
    for (int s = 0; s < 270; ++s) {
        const ull* rL = baseL + (s & 1) * 768;
        const ull* rM = baseM + (s & 1) * 768;
        ull* wLp = baseL + ((s + 1) & 1) * 768;
        ull* wMp = baseM + ((s + 1) & 1) * 768;
        const unsigned want = (unsigned)s;
        ull v0, v1, v2;
        bool got = false;
        for (int t = 0; t < 32; ++t) {
            asm volatile(
                "global_load_dwordx2 %0, %3, off sc0\n\t"
                "global_load_dwordx2 %1, %4, off sc0\n\t"
                "global_load_dwordx2 %2, %5, off sc0\n\t"
                "s_waitcnt vmcnt(0)"
                : "=&v"(v0), "=&v"(v1), "=&v"(v2)
                : "v"(rL + tid), "v"(rL + tid + 256), "v"(rL + tid + 512)
                : "memory");
            if (((unsigned)(v0 >> 32) == want) && ((unsigned)(v1 >> 32) == want) &&
                ((unsigned)(v2 >> 32) == want)) { got = true; break; }
        }
        if (!got) {  // straggler / placement fallback: MALL mirror (always correct)
            for (;;) {
                v0 = __hip_atomic_load(rM + tid, __ATOMIC_RELAXED, __HIP_MEMORY_SCOPE_AGENT);
                v1 = __hip_atomic_load(rM + tid + 256, __ATOMIC_RELAXED, __HIP_MEMORY_SCOPE_AGENT);
                v2 = __hip_atomic_load(rM + tid + 512, __ATOMIC_RELAXED, __HIP_MEMORY_SCOPE_AGENT);
                if (((unsigned)(v0 >> 32) == want) && ((unsigned)(v1 >> 32) == want) &&
                    ((unsigned)(v2 >> 32) == want)) break;
                __builtin_amdgcn_s_sleep(1);
            }
        }
        float f0 = __uint_as_float((unsigned)v0);
        float f1 = __uint_as_float((unsigned)v1);
        float f2 = __uint_as_float((unsigned)v2);
        hs32[tid] = f0;         hsf[tid] = (f16)f0;
        hs32[tid + 256] = f1;   hsf[tid + 256] = (f16)f1;
        hs32[tid + 512] = f2;   hsf[tid + 512] = (f16)f2;
        __syncthreads();                     // A: h_s staged
        float hold = 0.f, g0 = 0.f, g1 = 0.f, g2v = 0.f;
        if (tid < 32) {
            int c = u0 + tid;
            hold = hs32[c];
            const float* gp = gi + ((long)chain * 270 + s) * H3;
            g0 = gp[c];
            g1 = gp[H_ + c];
            g2v = gp[2 * H_ + c];
        }
        float ar = 0.f, az = 0.f, an = 0.f;
#pragma unroll
        for (int i = 0; i < 12; ++i) {
            ui4v hv = *(const ui4v*)(&hsf[(q * 12 + i) * 8]);
            ui4v wr = wreg[0][i], wz = wreg[1][i], wn = wreg[2][i];
            ar = fd2(hv.x, wr.x, ar); ar = fd2(hv.y, wr.y, ar);
            ar = fd2(hv.z, wr.z, ar); ar = fd2(hv.w, wr.w, ar);
            az = fd2(hv.x, wz.x, az); az = fd2(hv.y, wz.y, az);
            az = fd2(hv.z, wz.z, az); az = fd2(hv.w, wz.w, az);
            an = fd2(hv.x, wn.x, an); an = fd2(hv.y, wn.y, an);
            an = fd2(hv.z, wn.z, an); an = fd2(hv.w, wn.w, an);
        }
        part[q][u][0] = ar;
        part[q][u][1] = az;
        part[q][u][2] = an;
        __syncthreads();                     // B: partials ready, hsf reads done
        if (tid < 32) {
            float gr = b_r, gz = b_z, gn = b_n;
#pragma unroll
            for (int qq = 0; qq < 8; ++qq) {
                gr += part[qq][tid][0];
                gz += part[qq][tid][1];
                gn += part[qq][tid][2];
            }
            float rg = 1.f / (1.f + expf(-(g0 + gr)));
            float zg = 1.f / (1.f + expf(-(g1 + gz)));
            float ng = tanhf(g2v + rg * gn);
            float hnew = (1.f - zg) * ng + zg * hold;
            int c = u0 + tid;
            ull wv = ((ull)(unsigned)(s + 1) << 32) | (ull)__float_as_uint(hnew);
            wLp[c] = wv;                                   // L2 (same-XCD readers)
            __hip_atomic_store(wMp + c, wv, __ATOMIC_RELAXED, __HIP_MEMORY_SCOPE_AGENT);
            long row = (long)chain * 270 + s;
            f16 hi16 = (f16)hnew;
            Hhi[row * H_ + c] = hi16;
            Hlo[row * H_ + c] = (f16)(hnew - (float)hi16);
        }
        // no end barrier needed: next poll self-synchronizes on the data words
    }
}

// ---------------------------------------------------------------- attention softmax
__global__ __launch_bounds__(256) void k_attn_softmax(const float* __restrict__ lg,
                                                      const int* __restrict__ x, f16* __restrict__ ah) {
    __shared__ float red[256];
    int r = blockIdx.x, tid = threadIdx.x;
    int b = r / 270;
    const float* lr = lg + (long)r * S_;
    const int* xb = x + (long)b * S_;
    float v0 = lr[tid];
    if (xb[tid] == 0) v0 = -1e9f;
    float v1 = lr[tid + 256];
    if (xb[tid + 256] == 0) v1 = -1e9f;
    red[tid] = fmaxf(v0, v1);
    __syncthreads();
    for (int o = 128; o > 0; o >>= 1) {
        if (tid < o) red[tid] = fmaxf(red[tid], red[tid + o]);
        __syncthreads();
    }
    float m = red[0];
    __syncthreads();
    float e0 = __expf(v0 - m), e1 = __expf(v1 - m);
    red[tid] = e0 + e1;
    __syncthreads();
    for (int o = 128; o > 0; o >>= 1) {
        if (tid < o) red[tid] += red[tid + o];
        __syncthreads();
    }
    float inv = 1.f / red[0];
    ah[(long)r * S_ + tid] = (f16)(e0 * inv);
    ah[(long)r * S_ + tid + 256] = (f16)(e1 * inv);
}

// ---------------------------------------------------------------- p_gen
__global__ __launch_bounds__(256) void k_pgen(const f16* __restrict__ Wall, const f16* __restrict__ Hhi,
                                              const f16* __restrict__ Hlo, const float* __restrict__ ctx,
                                              const float* __restrict__ wg, const float* __restrict__ wgb,
                                              float* __restrict__ pg) {
    __shared__ float red[256];
    int r = blockIdx.x, tid = threadIdx.x;
    float a = 0.f;
    for (int i = tid; i < H_; i += 256) {
        a += (float)Wall[(long)r * H_ + i] * wg[i];
        a += ((float)Hhi[(long)r * H_ + i] + (float)Hlo[(long)r * H_ + i]) * wg[H_ + i];
        a += ctx[(long)r * H_ + i] * wg[2 * H_ + i];
    }
    red[tid] = a;
    __syncthreads();
    for (int o = 128; o > 0; o >>= 1) {
        if (tid < o) red[tid] += red[tid + o];
        __syncthreads();
    }
    if (tid == 0) pg[r] = 1.f / (1.f + expf(-(red[0] + wgb[0])));
}

// ---------------------------------------------------------------- vocab softmax stats (online)
__global__ __launch_bounds__(256) void k_rowstat(const float* __restrict__ out, float* __restrict__ rm,
                                                 float* __restrict__ rinv) {
    __shared__ float rm_s[256], rs_s[256];
    int r = blockIdx.x, tid = threadIdx.x;
    const f32x4* p = (const f32x4*)(out + (long)r * V_);
    float m = -3e38f, ssum = 0.f;
    for (int i = tid; i < V_ / 4; i += 256) {
        f32x4 v = p[i];
        float mv = fmaxf(fmaxf(v.x, v.y), fmaxf(v.z, v.w));
        if (mv > m) {
            ssum *= __expf(m - mv);
            m = mv;
        }
        ssum += __expf(v.x - m) + __expf(v.y - m) + __expf(v.z - m) + __expf(v.w - m);
    }
    rm_s[tid] = m;
    rs_s[tid] = ssum;
    __syncthreads();
    for (int o = 128; o > 0; o >>= 1) {
        if (tid < o) {
            float m2 = rm_s[tid + o], s2 = rs_s[tid + o];
            float M = fmaxf(rm_s[tid], m2);
            rs_s[tid] = rs_s[tid] * __expf(rm_s[tid] - M) + s2 * __expf(m2 - M);
            rm_s[tid] = M;
        }
        __syncthreads();
    }
    if (tid == 0) {
        rm[r] = rm_s[0];
        rinv[r] = 1.f / rs_s[0];
    }
}

// ---------------------------------------------------------------- finalize: p_gen * softmax (in place)
__global__ __launch_bounds__(256) void k_final(float* __restrict__ out, const float* __restrict__ rm,
                                               const float* __restrict__ rinv, const float* __restrict__ pg) {
    int r = blockIdx.y;
    int i = blockIdx.x * 256 + threadIdx.x;
    if (i >= V_ / 4) return;
    float m = rm[r], inv = rinv[r], p = pg[r];
    f32x4* po = (f32x4*)(out + (long)r * V_);
    f32x4 v = po[i];
    v.x = p * __expf(v.x - m) * inv;
    v.y = p * __expf(v.y - m) * inv;
    v.z = p * __expf(v.z - m) * inv;
    v.w = p * __expf(v.w - m) * inv;
    po[i] = v;
}

// ---------------------------------------------------------------- pointer scatter
__global__ __launch_bounds__(512) void k_scatter(float* __restrict__ out, const f16* __restrict__ ah,
                                                 const float* __restrict__ pg, const int* __restrict__ x) {
    int r = blockIdx.x, s = threadIdx.x;
    int b = r / 270;
    int xv = x[(long)b * S_ + s];
    if (xv == 0) return;
    float a = (float)ah[(long)r * S_ + s];
    if (a == 0.f) return;
    atomicAdd(out + (long)r * V_ + xv, (1.f - pg[r]) * a);
}

// ---------------------------------------------------------------- host
extern "C" void kernel_launch(void* const* d_in, const int* in_sizes, int n_in, void* d_out,
                              int out_size, void* d_ws, size_t ws_size, hipStream_t stream) {
    (void)in_sizes; (void)n_in; (void)out_size; (void)ws_size;
    const int* x = (const int*)d_in[0];
    const float* dec = (const float*)d_in[1];
    const float* enc = (const float*)d_in[2];
    const float* hid = (const float*)d_in[3];
    const int* tea = (const int*)d_in[4];
    const float* emb = (const float*)d_in[6];
    const float* wih = (const float*)d_in[7];
    const float* whh = (const float*)d_in[8];
    const float* bih = (const float*)d_in[9];
    const float* bhh = (const float*)d_in[10];
    const float* wgw = (const float*)d_in[11];
    const float* wgb = (const float*)d_in[12];
    float* out = (float*)d_out;

    char* w = (char*)d_ws;
    size_t off = 0;
    auto alloc = [&](size_t bytes) {
        void* p = w + off;
        off = (off + bytes + 255) & ~(size_t)255;
        return p;
    };
    int* roster = (int*)alloc(32);                      // 8 counters (padded to 256)
    ull* hbufL = (ull*)alloc(8 * 1536 * 8);             // [chain][parity][768] L2 copy
    ull* hbufM = (ull*)alloc(8 * 1536 * 8);             // MALL mirror
    f16* Wall = (f16*)alloc((size_t)R_ * H_ * 2);
    f16* wih16 = (f16*)alloc((size_t)H3 * H_ * 2);
    f16* wh16 = (f16*)alloc((size_t)H3 * H_ * 2);
    float* giA = (float*)alloc((size_t)R_ * H3 * 4);
    f16* Hhi = (f16*)alloc((size_t)R_ * H_ * 2);
    f16* Hlo = (f16*)alloc((size_t)R_ * H_ * 2);
    f16* emb16 = (f16*)alloc((size_t)V_ * H_ * 2);
    f16* ehi = (f16*)alloc((size_t)B_ * S_ * H_ * 2);
    f16* elo = (f16*)alloc((size_t)B_ * S_ * H_ * 2);
    f16* encT = (f16*)alloc((size_t)B_ * H_ * S_ * 2);
    float* lgH = (float*)alloc((size_t)R_ * S_ * 4);
    f16* ah = (f16*)alloc((size_t)R_ * S_ * 2);
    float* ctx = (float*)alloc((size_t)R_ * H_ * 4);
    float* pg = (float*)alloc(R_ * 4);
    float* rm = (float*)alloc(R_ * 4);
    float* rinv = (float*)alloc(R_ * 4);

    // roster + both h buffers are contiguous from roster: (256 + 2*98304)/4 ints
    const int nZero = (256 + 2 * 8 * 1536 * 8) / 4;
    k_zero<<<(nZero + 255) / 256, 256, 0, stream>>>(roster, nZero);
    k_cast<<<2048, 256, 0, stream>>>(emb, emb16, (long)V_ * H_);
    k_cast<<<512, 256, 0, stream>>>(wih, wih16, (long)H3 * H_);
    k_cast<<<512, 256, 0, stream>>>(whh, wh16, (long)H3 * H_);
    k_build_wall<<<R_, 256, 0, stream>>>(emb, dec, tea, Wall);
    k_build_enc<<<1024, 256, 0, stream>>>(enc, ehi, elo, encT);
    k_init_h<<<24, 256, 0, stream>>>(hid, hbufL, hbufM);

    // gi = W_all @ w_ih^T + b_ih
    {
        dim3 g(H3 / 128, (R_ + 127) / 128, 1);
        k_gemm<1><<<g, 256, 0, stream>>>(Wall, wih16, giA, bih, R_, H3, H_, 0, 0, 0);
    }
    k_gru<<<256, 256, 0, stream>>>(giA, wh16, bhh, hbufL, hbufM, Hhi, Hlo, roster);

    // attention logits, hi/lo split: Hhi*Ehi + Hhi*Elo + Hlo*Ehi
    {
        dim3 g(S_ / 128, 3, 8);
        k_gemm<0><<<g, 256, 0, stream>>>(Hhi, ehi, lgH, nullptr, 270, S_, H_, 270L * H_, (long)S_ * H_, 270L * S_);
        k_gemm<2><<<g, 256, 0, stream>>>(Hhi, elo, lgH, nullptr, 270, S_, H_, 270L * H_, (long)S_ * H_, 270L * S_);
        k_gemm<2><<<g, 256, 0, stream>>>(Hlo, ehi, lgH, nullptr, 270, S_, H_, 270L * H_, (long)S_ * H_, 270L * S_);
    }
    k_attn_softmax<<<R_, 256, 0, stream>>>(lgH, x, ah);
    {
        dim3 g(H_ / 128, 3, 8);
        k_gemm<0><<<g, 256, 0, stream>>>(ah, encT, ctx, nullptr, 270, H_, S_, 270L * S_, (long)H_ * S_, 270L * H_);
    }
    k_pgen<<<R_, 256, 0, stream>>>(Wall, Hhi, Hlo, ctx, wgw, wgb, pg);

    // vocab logits straight into d_out
    {
        dim3 g((V_ + 127) / 128, (R_ + 127) / 128, 1);
        k_gemm<0><<<g, 256, 0, stream>>>(Hhi, emb16, out, nullptr, R_, V_, H_, 0, 0, 0);
    }
    k_rowstat<<<R_, 256, 0, stream>>>(out, rm, rinv);
    {
        dim3 g((V_ / 4 + 255) / 256, R_, 1);
        k_final<<<g, 256, 0, stream>>>(out, rm, rinv, pg);
    }
    k_scatter<<<R_, 512, 0, stream>>>(out, ah, pg, x);
}

// Round 7
// 1552.197 us; speedup vs baseline: 1.4206x; 1.4206x over previous
//
#include <hip/hip_runtime.h>
#include <hip/hip_bf16.h>

typedef _Float16 f16;
typedef _Float16 f16x8 __attribute__((ext_vector_type(8)));
typedef float f32x4 __attribute__((ext_vector_type(4)));
typedef unsigned long long ull;

#define B_ 8
#define S_ 512
#define H_ 768
#define V_ 35004
#define J_ 30
#define K_ 9
#define R_ 2160          // B*J*K rows, row r = b*270 + j*9 + t  (matches out layout)
#define H3 2304
#define NGRP 4           // batch-pair groups
#define GBLK 48          // blocks per group
#define UPB 16           // hidden units per block

// ---------------------------------------------------------------- prep kernels

__global__ void k_zero(int* p, int n) {
    int i = blockIdx.x * 256 + threadIdx.x;
    if (i < n) p[i] = 0;
}

__global__ void k_cast(const float* __restrict__ s, f16* __restrict__ d, long n) {
    for (long i = (long)blockIdx.x * 256 + threadIdx.x; i < n; i += (long)gridDim.x * 256)
        d[i] = (f16)s[i];
}

// W_all[r] = (t==0) ? decoder_input[b,j,:] : embed[teacher[b,j,t-1],:]
__global__ void k_build_wall(const float* __restrict__ emb, const float* __restrict__ dec,
                             const int* __restrict__ teacher, f16* __restrict__ Wall) {
    int r = blockIdx.x;
    int b = r / 270, s = r % 270, j = s / 9, t = s % 9;
    const float* src = (t == 0) ? dec + ((long)b * J_ + j) * H_
                                : emb + (long)teacher[((long)b * J_ + j) * K_ + (t - 1)] * H_;
    f16* dst = Wall + (long)r * H_;
    for (int c = threadIdx.x; c < H_; c += 256) dst[c] = (f16)src[c];
}

// enc hi/lo split (row-major [b][s][h]) + encT hi ([b][h][s]) for context GEMM
__global__ void k_build_enc(const float* __restrict__ enc, f16* __restrict__ ehi,
                            f16* __restrict__ elo, f16* __restrict__ encT) {
    long n = (long)B_ * S_ * H_;
    for (long i = (long)blockIdx.x * 256 + threadIdx.x; i < n; i += (long)gridDim.x * 256) {
        float v = enc[i];
        f16 hi = (f16)v;
        ehi[i] = hi;
        elo[i] = (f16)(v - (float)hi);
        int h = (int)(i % H_);
        long bs = i / H_;
        int s = (int)(bs % S_), b = (int)(bs / S_);
        encT[((long)b * H_ + h) * S_ + s] = hi;
    }
}

// h exchange word: {seq:32 | f32 bits:32}. Parity-0 region gets seq=0 initial h.
__global__ void k_init_h(const float* __restrict__ hidden, ull* __restrict__ hbuf) {
    int i = blockIdx.x * 256 + threadIdx.x;
    if (i < B_ * H_) {
        int b = i / H_, u = i % H_;
        unsigned bits = __float_as_uint(hidden[i]);
        hbuf[(long)(b >> 1) * 1536 + (b & 1) * 768 + u] = (ull)bits;  // seq 0
    }
}

// ---------------------------------------------------------------- f16 MFMA GEMM (m97 structure)
// C[M,N] = A[M,K] @ B[N,K]^T ; MODE 0: store, 1: store + bias[col], 2: C += result
// Staging via global_load_lds width=16: LDS dest = wave-uniform base + lane*16,
// global src per-lane. Linear LDS [128 rows][32 f16]. Edge rows/cols clamped
// (garbage rows discarded by the masked C-write).
typedef const __attribute__((address_space(1))) unsigned GASU;
typedef __attribute__((address_space(3))) unsigned LASU;
__device__ __forceinline__ void gld16(const f16* g, f16* l) {
    __builtin_amdgcn_global_load_lds((GASU*)g, (LASU*)l, 16, 0, 0);
}

template <int MODE>
__global__ __launch_bounds__(256) void k_gemm(const f16* __restrict__ A, const f16* __restrict__ Bm,
                                              float* __restrict__ C, const float* __restrict__ bias,
                                              int M, int N, int K, long sA, long sB, long sC) {
    A += (long)blockIdx.z * sA;
    Bm += (long)blockIdx.z * sB;
    C += (long)blockIdx.z * sC;
    const int m0 = blockIdx.y * 128, n0 = blockIdx.x * 128;
    __shared__ f16 As[128 * 32];
    __shared__ f16 Bs[128 * 32];
    const int tid = threadIdx.x, lane = tid & 63, wave = tid >> 6;
    const int wm = wave >> 1, wn = wave & 1;
    const int fr = lane & 15, kg = lane >> 4;
    f32x4 acc[4][4] = {};
    const int idxu = wave * 128;                 // uniform 16B-unit base for this wave
    const int i0 = idxu + lane, i1 = idxu + 64 + lane;
    const int r0 = i0 >> 2, k80 = i0 & 3;
    const int r1 = i1 >> 2, k81 = i1 & 3;
    int ga0 = m0 + r0; if (ga0 >= M) ga0 = M - 1;
    int ga1 = m0 + r1; if (ga1 >= M) ga1 = M - 1;
    int gb0 = n0 + r0; if (gb0 >= N) gb0 = N - 1;
    int gb1 = n0 + r1; if (gb1 >= N) gb1 = N - 1;
    const f16* pa0 = A + (long)ga0 * K + k80 * 8;
    const f16* pa1 = A + (long)ga1 * K + k81 * 8;
    const f16* pb0 = Bm + (long)gb0 * K + k80 * 8;
    const f16* pb1 = Bm + (long)gb1 * K + k81 * 8;
    for (int kt = 0; kt < K; kt += 32) {
        gld16(pa0 + kt, As + idxu * 8);
        gld16(pa1 + kt, As + idxu * 8 + 512);
        gld16(pb0 + kt, Bs + idxu * 8);
        gld16(pb1 + kt, Bs + idxu * 8 + 512);
        __syncthreads();                         // drains vmcnt -> tiles resident
        f16x8 af[4], bf[4];
#pragma unroll
        for (int m = 0; m < 4; ++m) af[m] = *(const f16x8*)(As + (wm * 64 + m * 16 + fr) * 32 + kg * 8);
#pragma unroll
        for (int n = 0; n < 4; ++n) bf[n] = *(const f16x8*)(Bs + (wn * 64 + n * 16 + fr) * 32 + kg * 8);
#pragma unroll
        for (int m = 0; m < 4; ++m)
#pragma unroll
            for (int n = 0; n < 4; ++n)
                acc[m][n] = __builtin_amdgcn_mfma_f32_16x16x32_f16(af[m], bf[n], acc[m][n], 0, 0, 0);
        __syncthreads();
    }
    const int crow = m0 + wm * 64 + (lane >> 4) * 4;
    const int ccol = n0 + wn * 64 + fr;
#pragma unroll
    for (int n = 0; n < 4; ++n) {
        int col = ccol + n * 16;
        if (col >= N) continue;
        float bv = (MODE == 1) ? bias[col] : 0.f;
#pragma unroll
        for (int m = 0; m < 4; ++m) {
#pragma unroll
            for (int q = 0; q < 4; ++q) {
                int row = crow + m * 16 + q;
                if (row < M) {
                    long idx = (long)row * N + col;
                    float v = acc[m][n][q] + bv;
                    if (MODE == 2) v += C[idx];
                    C[idx] = v;
                }
            }
        }
    }
}

// ---------------------------------------------------------------- GRU recurrence  (R5, proven)
// 192 blocks = 4 batch-pair groups x 48 blocks x 16 units; f32 weights in LDS.
// h exchange: each value is a ull {seq<<32 | f32} stored with ONE relaxed
// agent atomic; readers poll their 6 words for seq==s. Data dependency bounds
// block spread to 1 step -> parity double-buffer, no flags, no global barrier.
__global__ __launch_bounds__(256) void k_gru(const float* __restrict__ gi,
                                             const float* __restrict__ whh,
                                             const float* __restrict__ bhh,
                                             ull* hbuf,
                                             f16* __restrict__ Hhi, f16* __restrict__ Hlo) {
    __shared__ f32x4 wsv[3 * 192 * 16];   // [g][k4][u] : 147456 B
    __shared__ float hs[2][776];          // h for the 2 batches of the pair
    __shared__ float part[8][32][3];
    const int tid = threadIdx.x;
    const int bp = blockIdx.x / GBLK;     // batch-pair group 0..3
    const int blk = blockIdx.x % GBLK;
    const int u0 = blk * UPB;
    for (int idx = tid; idx < 3 * 192 * 16; idx += 256) {
        int uu = idx & 15, k4 = (idx >> 4) % 192, g = idx / (192 * 16);
        wsv[idx] = *(const f32x4*)(whh + (long)(g * H_ + u0 + uu) * H_ + k4 * 4);
    }
    float b_r = 0.f, b_z = 0.f, b_n = 0.f;
    if (tid < 32) {
        int c = u0 + (tid & 15);
        b_r = bhh[c];
        b_z = bhh[H_ + c];
        b_n = bhh[2 * H_ + c];
    }
    __syncthreads();
    const int u = tid & 15, b2 = (tid >> 4) & 1, q = tid >> 5;
    ull* base0 = hbuf + (long)bp * 1536;
    ull* base1 = hbuf + (long)NGRP * 1536 + (long)bp * 1536;
    for (int s = 0; s < 270; ++s) {
        ull* rbuf = (s & 1) ? base1 : base0;
        ull* wbuf = (s & 1) ? base0 : base1;
        const unsigned want = (unsigned)s;
        ull v0, v1, v2, v3, v4, v5;
        for (;;) {
            v0 = __hip_atomic_load(rbuf + tid, __ATOMIC_RELAXED, __HIP_MEMORY_SCOPE_AGENT);
            v1 = __hip_atomic_load(rbuf + tid + 256, __ATOMIC_RELAXED, __HIP_MEMORY_SCOPE_AGENT);
            v2 = __hip_atomic_load(rbuf + tid + 512, __ATOMIC_RELAXED, __HIP_MEMORY_SCOPE_AGENT);
            v3 = __hip_atomic_load(rbuf + tid + 768, __ATOMIC_RELAXED, __HIP_MEMORY_SCOPE_AGENT);
            v4 = __hip_atomic_load(rbuf + tid + 1024, __ATOMIC_RELAXED, __HIP_MEMORY_SCOPE_AGENT);
            v5 = __hip_atomic_load(rbuf + tid + 1280, __ATOMIC_RELAXED, __HIP_MEMORY_SCOPE_AGENT);
            bool ok = ((unsigned)(v0 >> 32) == want) & ((unsigned)(v1 >> 32) == want) &
                      ((unsigned)(v2 >> 32) == want) & ((unsigned)(v3 >> 32) == want) &
                      ((unsigned)(v4 >> 32) == want) & ((unsigned)(v5 >> 32) == want);
            if (ok) break;
        }
        {
            ull vv[6] = {v0, v1, v2, v3, v4, v5};
#pragma unroll
            for (int k = 0; k < 6; ++k) {
                int i = tid + k * 256;
                int bb2 = i / 768, uu = i - bb2 * 768;
                hs[bb2][uu] = __uint_as_float((unsigned)vv[k]);
            }
        }
        __syncthreads();                       // hs(s) ready
        float hold = 0.f, g0 = 0.f, g1 = 0.f, g2 = 0.f;
        if (tid < 32) {
            int c = u0 + (tid & 15);
            hold = hs[tid >> 4][c];
            long row = (long)(bp * 2 + (tid >> 4)) * 270 + s;
            const float* gp = gi + row * H3;
            g0 = gp[c];
            g1 = gp[H_ + c];
            g2 = gp[2 * H_ + c];
        }
        float ar = 0.f, az = 0.f, an = 0.f;
        const float* hb = &hs[b2][0];
#pragma unroll 4
        for (int i = 0; i < 24; ++i) {
            int k4 = i * 8 + q;
            f32x4 hv = *(const f32x4*)(hb + k4 * 4);
            f32x4 wr = wsv[k4 * 16 + u];
            f32x4 wz = wsv[(192 + k4) * 16 + u];
            f32x4 wn = wsv[(384 + k4) * 16 + u];
            ar += hv.x * wr.x + hv.y * wr.y + hv.z * wr.z + hv.w * wr.w;
            az += hv.x * wz.x + hv.y * wz.y + hv.z * wz.z + hv.w * wz.w;
            an += hv.x * wn.x + hv.y * wn.y + hv.z * wn.z + hv.w * wn.w;
        }
        int oi = (b2 << 4) | u;
        part[q][oi][0] = ar;
        part[q][oi][1] = az;
        part[q][oi][2] = an;
        __syncthreads();                       // partials ready; hs reads done
        if (tid < 32) {
            float gr = b_r, gz = b_z, gn = b_n;
#pragma unroll
            for (int qq = 0; qq < 8; ++qq) {
                gr += part[qq][tid][0];
                gz += part[qq][tid][1];
                gn += part[qq][tid][2];
            }
            int c = u0 + (tid & 15);
            int bb = bp * 2 + (tid >> 4);
            long row = (long)bb * 270 + s;
            float rg = 1.f / (1.f + expf(-(g0 + gr)));
            float zg = 1.f / (1.f + expf(-(g1 + gz)));
            float ng = tanhf(g2 + rg * gn);
            float hnew = (1.f - zg) * ng + zg * hold;
            ull wv = ((ull)(unsigned)(s + 1) << 32) | (ull)__float_as_uint(hnew);
            __hip_atomic_store(wbuf + (bb & 1) * 768 + c, wv,
                               __ATOMIC_RELAXED, __HIP_MEMORY_SCOPE_AGENT);
            f16 hi16 = (f16)hnew;
            Hhi[row * H_ + c] = hi16;
            Hlo[row * H_ + c] = (f16)(hnew - (float)hi16);
        }
        // no barrier: stores drain while everyone polls the next step
    }
}

// ---------------------------------------------------------------- attention softmax
__global__ __launch_bounds__(256) void k_attn_softmax(const float* __restrict__ lg,
                                                      const int* __restrict__ x, f16* __restrict__ ah) {
    __shared__ float red[256];
    int r = blockIdx.x, tid = threadIdx.x;
    int b = r / 270;
    const float* lr = lg + (long)r * S_;
    const int* xb = x + (long)b * S_;
    float v0 = lr[tid];
    if (xb[tid] == 0) v0 = -1e9f;
    float v1 = lr[tid + 256];
    if (xb[tid + 256] == 0) v1 = -1e9f;
    red[tid] = fmaxf(v0, v1);
    __syncthreads();
    for (int o = 128; o > 0; o >>= 1) {
        if (tid < o) red[tid] = fmaxf(red[tid], red[tid + o]);
        __syncthreads();
    }
    float m = red[0];
    __syncthreads();
    float e0 = __expf(v0 - m), e1 = __expf(v1 - m);
    red[tid] = e0 + e1;
    __syncthreads();
    for (int o = 128; o > 0; o >>= 1) {
        if (tid < o) red[tid] += red[tid + o];
        __syncthreads();
    }
    float inv = 1.f / red[0];
    ah[(long)r * S_ + tid] = (f16)(e0 * inv);
    ah[(long)r * S_ + tid + 256] = (f16)(e1 * inv);
}

// ---------------------------------------------------------------- p_gen
__global__ __launch_bounds__(256) void k_pgen(const f16* __restrict__ Wall, const f16* __restrict__ Hhi,
                                              const f16* __restrict__ Hlo, const float* __restrict__ ctx,
                                              const float* __restrict__ wg, const float* __restrict__ wgb,
                                              float* __restrict__ pg) {
    __shared__ float red[256];
    int r = blockIdx.x, tid = threadIdx.x;
    float a = 0.f;
    for (int i = tid; i < H_; i += 256) {
        a += (float)Wall[(long)r * H_ + i] * wg[i];
        a += ((float)Hhi[(long)r * H_ + i] + (float)Hlo[(long)r * H_ + i]) * wg[H_ + i];
        a += ctx[(long)r * H_ + i] * wg[2 * H_ + i];
    }
    red[tid] = a;
    __syncthreads();
    for (int o = 128; o > 0; o >>= 1) {
        if (tid < o) red[tid] += red[tid + o];
        __syncthreads();
    }
    if (tid == 0) pg[r] = 1.f / (1.f + expf(-(red[0] + wgb[0])));
}

// ---------------------------------------------------------------- vocab softmax stats (online)
__global__ __launch_bounds__(256) void k_rowstat(const float* __restrict__ out, float* __restrict__ rm,
                                                 float* __restrict__ rinv) {
    __shared__ float rm_s[256], rs_s[256];
    int r = blockIdx.x, tid = threadIdx.x;
    const f32x4* p = (const f32x4*)(out + (long)r * V_);
    float m = -3e38f, ssum = 0.f;
    for (int i = tid; i < V_ / 4; i += 256) {
        f32x4 v = p[i];
        float mv = fmaxf(fmaxf(v.x, v.y), fmaxf(v.z, v.w));
        if (mv > m) {
            ssum *= __expf(m - mv);
            m = mv;
        }
        ssum += __expf(v.x - m) + __expf(v.y - m) + __expf(v.z - m) + __expf(v.w - m);
    }
    rm_s[tid] = m;
    rs_s[tid] = ssum;
    __syncthreads();
    for (int o = 128; o > 0; o >>= 1) {
        if (tid < o) {
            float m2 = rm_s[tid + o], s2 = rs_s[tid + o];
            float M = fmaxf(rm_s[tid], m2);
            rs_s[tid] = rs_s[tid] * __expf(rm_s[tid] - M) + s2 * __expf(m2 - M);
            rm_s[tid] = M;
        }
        __syncthreads();
    }
    if (tid == 0) {
        rm[r] = rm_s[0];
        rinv[r] = 1.f / rs_s[0];
    }
}

// ---------------------------------------------------------------- finalize: p_gen * softmax (in place)
__global__ __launch_bounds__(256) void k_final(float* __restrict__ out, const float* __restrict__ rm,
                                               const float* __restrict__ rinv, const float* __restrict__ pg) {
    int r = blockIdx.y;
    int i = blockIdx.x * 256 + threadIdx.x;
    if (i >= V_ / 4) return;
    float m = rm[r], inv = rinv[r], p = pg[r];
    f32x4* po = (f32x4*)(out + (long)r * V_);
    f32x4 v = po[i];
    v.x = p * __expf(v.x - m) * inv;
    v.y = p * __expf(v.y - m) * inv;
    v.z = p * __expf(v.z - m) * inv;
    v.w = p * __expf(v.w - m) * inv;
    po[i] = v;
}

// ---------------------------------------------------------------- pointer scatter
__global__ __launch_bounds__(512) void k_scatter(float* __restrict__ out, const f16* __restrict__ ah,
                                                 const float* __restrict__ pg, const int* __restrict__ x) {
    int r = blockIdx.x, s = threadIdx.x;
    int b = r / 270;
    int xv = x[(long)b * S_ + s];
    if (xv == 0) return;
    float a = (float)ah[(long)r * S_ + s];
    if (a == 0.f) return;
    atomicAdd(out + (long)r * V_ + xv, (1.f - pg[r]) * a);
}

// ---------------------------------------------------------------- host
extern "C" void kernel_launch(void* const* d_in, const int* in_sizes, int n_in, void* d_out,
                              int out_size, void* d_ws, size_t ws_size, hipStream_t stream) {
    (void)in_sizes; (void)n_in; (void)out_size; (void)ws_size;
    const int* x = (const int*)d_in[0];
    const float* dec = (const float*)d_in[1];
    const float* enc = (const float*)d_in[2];
    const float* hid = (const float*)d_in[3];
    const int* tea = (const int*)d_in[4];
    const float* emb = (const float*)d_in[6];
    const float* wih = (const float*)d_in[7];
    const float* whh = (const float*)d_in[8];
    const float* bih = (const float*)d_in[9];
    const float* bhh = (const float*)d_in[10];
    const float* wgw = (const float*)d_in[11];
    const float* wgb = (const float*)d_in[12];
    float* out = (float*)d_out;

    char* w = (char*)d_ws;
    size_t off = 0;
    auto alloc = [&](size_t bytes) {
        void* p = w + off;
        off = (off + bytes + 255) & ~(size_t)255;
        return p;
    };
    ull* hbuf = (ull*)alloc(2 * NGRP * 1536 * 8);   // [parity][pair][1536] seq-tagged h
    f16* Wall = (f16*)alloc((size_t)R_ * H_ * 2);
    f16* wih16 = (f16*)alloc((size_t)H3 * H_ * 2);
    float* giA = (float*)alloc((size_t)R_ * H3 * 4);
    f16* Hhi = (f16*)alloc((size_t)R_ * H_ * 2);
    f16* Hlo = (f16*)alloc((size_t)R_ * H_ * 2);
    f16* emb16 = (f16*)alloc((size_t)V_ * H_ * 2);
    f16* ehi = (f16*)alloc((size_t)B_ * S_ * H_ * 2);
    f16* elo = (f16*)alloc((size_t)B_ * S_ * H_ * 2);
    f16* encT = (f16*)alloc((size_t)B_ * H_ * S_ * 2);
    float* lgH = (float*)alloc((size_t)R_ * S_ * 4);
    f16* ah = (f16*)alloc((size_t)R_ * S_ * 2);
    float* ctx = (float*)alloc((size_t)R_ * H_ * 4);
    float* pg = (float*)alloc(R_ * 4);
    float* rm = (float*)alloc(R_ * 4);
    float* rinv = (float*)alloc(R_ * 4);

    const int nH = 2 * NGRP * 1536 * 2;             // hbuf as ints
    k_zero<<<(nH + 255) / 256, 256, 0, stream>>>((int*)hbuf, nH);
    k_cast<<<2048, 256, 0, stream>>>(emb, emb16, (long)V_ * H_);
    k_cast<<<512, 256, 0, stream>>>(wih, wih16, (long)H3 * H_);
    k_build_wall<<<R_, 256, 0, stream>>>(emb, dec, tea, Wall);
    k_build_enc<<<1024, 256, 0, stream>>>(enc, ehi, elo, encT);
    k_init_h<<<24, 256, 0, stream>>>(hid, hbuf);

    // gi = W_all @ w_ih^T + b_ih
    {
        dim3 g(H3 / 128, (R_ + 127) / 128, 1);
        k_gemm<1><<<g, 256, 0, stream>>>(Wall, wih16, giA, bih, R_, H3, H_, 0, 0, 0);
    }
    k_gru<<<NGRP * GBLK, 256, 0, stream>>>(giA, whh, bhh, hbuf, Hhi, Hlo);

    // attention logits, hi/lo split: Hhi*Ehi + Hhi*Elo + Hlo*Ehi
    {
        dim3 g(S_ / 128, 3, 8);
        k_gemm<0><<<g, 256, 0, stream>>>(Hhi, ehi, lgH, nullptr, 270, S_, H_, 270L * H_, (long)S_ * H_, 270L * S_);
        k_gemm<2><<<g, 256, 0, stream>>>(Hhi, elo, lgH, nullptr, 270, S_, H_, 270L * H_, (long)S_ * H_, 270L * S_);
        k_gemm<2><<<g, 256, 0, stream>>>(Hlo, ehi, lgH, nullptr, 270, S_, H_, 270L * H_, (long)S_ * H_, 270L * S_);
    }
    k_attn_softmax<<<R_, 256, 0, stream>>>(lgH, x, ah);
    {
        dim3 g(H_ / 128, 3, 8);
        k_gemm<0><<<g, 256, 0, stream>>>(ah, encT, ctx, nullptr, 270, H_, S_, 270L * S_, (long)H_ * S_, 270L * H_);
    }
    k_pgen<<<R_, 256, 0, stream>>>(Wall, Hhi, Hlo, ctx, wgw, wgb, pg);

    // vocab logits straight into d_out
    {
        dim3 g((V_ + 127) / 128, (R_ + 127) / 128, 1);
        k_gemm<0><<<g, 256, 0, stream>>>(Hhi, emb16, out, nullptr, R_, V_, H_, 0, 0, 0);
    }
    k_rowstat<<<R_, 256, 0, stream>>>(out, rm, rinv);
    {
        dim3 g((V_ / 4 + 255) / 256, R_, 1);
        k_final<<<g, 256, 0, stream>>>(out, rm, rinv, pg);
    }
    k_scatter<<<R_, 512, 0, stream>>>(out, ah, pg, x);
}

// Round 8
// 1220.876 us; speedup vs baseline: 1.8062x; 1.2714x over previous
//
#include <hip/hip_runtime.h>
#include <hip/hip_bf16.h>

typedef _Float16 f16;
typedef _Float16 f16x8 __attribute__((ext_vector_type(8)));
typedef _Float16 h2 __attribute__((ext_vector_type(2)));
typedef float f32x4 __attribute__((ext_vector_type(4)));
typedef unsigned ui4v __attribute__((ext_vector_type(4)));
typedef unsigned long long ull;

#define B_ 8
#define S_ 512
#define H_ 768
#define V_ 35004
#define J_ 30
#define K_ 9
#define R_ 2160          // B*J*K rows, row r = b*270 + j*9 + t  (matches out layout)
#define H3 2304
#define CBLK 24          // blocks per chain (one chain = one batch)
#define CUPB 32          // hidden units per block

// ---------------------------------------------------------------- prep kernels

__global__ void k_zero(int* p, int n) {
    int i = blockIdx.x * 256 + threadIdx.x;
    if (i < n) p[i] = 0;
}

__global__ void k_cast(const float* __restrict__ s, f16* __restrict__ d, long n) {
    for (long i = (long)blockIdx.x * 256 + threadIdx.x; i < n; i += (long)gridDim.x * 256)
        d[i] = (f16)s[i];
}

// W_all[r] = (t==0) ? decoder_input[b,j,:] : embed[teacher[b,j,t-1],:]
__global__ void k_build_wall(const float* __restrict__ emb, const float* __restrict__ dec,
                             const int* __restrict__ teacher, f16* __restrict__ Wall) {
    int r = blockIdx.x;
    int b = r / 270, s = r % 270, j = s / 9, t = s % 9;
    const float* src = (t == 0) ? dec + ((long)b * J_ + j) * H_
                                : emb + (long)teacher[((long)b * J_ + j) * K_ + (t - 1)] * H_;
    f16* dst = Wall + (long)r * H_;
    for (int c = threadIdx.x; c < H_; c += 256) dst[c] = (f16)src[c];
}

// enc hi/lo split (row-major [b][s][h]) + encT hi ([b][h][s]) for context GEMM
__global__ void k_build_enc(const float* __restrict__ enc, f16* __restrict__ ehi,
                            f16* __restrict__ elo, f16* __restrict__ encT) {
    long n = (long)B_ * S_ * H_;
    for (long i = (long)blockIdx.x * 256 + threadIdx.x; i < n; i += (long)gridDim.x * 256) {
        float v = enc[i];
        f16 hi = (f16)v;
        ehi[i] = hi;
        elo[i] = (f16)(v - (float)hi);
        int h = (int)(i % H_);
        long bs = i / H_;
        int s = (int)(bs % S_), b = (int)(bs / S_);
        encT[((long)b * H_ + h) * S_ + s] = hi;
    }
}

// h exchange word: {seq:32 | f32 bits:32}; chain-major [chain][parity][768]
__global__ void k_init_h(const float* __restrict__ hidden, ull* __restrict__ hbuf) {
    int i = blockIdx.x * 256 + threadIdx.x;
    if (i < B_ * H_) {
        int b = i / H_, u = i % H_;
        hbuf[(long)b * 1536 + u] = (ull)__float_as_uint(hidden[i]);  // seq 0, parity 0
    }
}

// ---------------------------------------------------------------- f16 MFMA GEMM (m97 structure)
// C[M,N] = A[M,K] @ B[N,K]^T
// MODE 0: store, 1: store + bias[col], 2: C += result,
// MODE 3: C = exp(result), per-block per-row partial sums -> psum[blockIdx.x][row]
typedef const __attribute__((address_space(1))) unsigned GASU;
typedef __attribute__((address_space(3))) unsigned LASU;
__device__ __forceinline__ void gld16(const f16* g, f16* l) {
    __builtin_amdgcn_global_load_lds((GASU*)g, (LASU*)l, 16, 0, 0);
}

template <int MODE>
__global__ __launch_bounds__(256) void k_gemm(const f16* __restrict__ A, const f16* __restrict__ Bm,
                                              float* __restrict__ C, const float* __restrict__ bias,
                                              int M, int N, int K, long sA, long sB, long sC,
                                              float* __restrict__ psum) {
    A += (long)blockIdx.z * sA;
    Bm += (long)blockIdx.z * sB;
    C += (long)blockIdx.z * sC;
    const int m0 = blockIdx.y * 128, n0 = blockIdx.x * 128;
    __shared__ f16 As[128 * 32];
    __shared__ f16 Bs[128 * 32];
    __shared__ float rpart[2][128];
    const int tid = threadIdx.x, lane = tid & 63, wave = tid >> 6;
    const int wm = wave >> 1, wn = wave & 1;
    const int fr = lane & 15, kg = lane >> 4;
    f32x4 acc[4][4] = {};
    const int idxu = wave * 128;                 // uniform 16B-unit base for this wave
    const int i0 = idxu + lane, i1 = idxu + 64 + lane;
    const int r0 = i0 >> 2, k80 = i0 & 3;
    const int r1 = i1 >> 2, k81 = i1 & 3;
    int ga0 = m0 + r0; if (ga0 >= M) ga0 = M - 1;
    int ga1 = m0 + r1; if (ga1 >= M) ga1 = M - 1;
    int gb0 = n0 + r0; if (gb0 >= N) gb0 = N - 1;
    int gb1 = n0 + r1; if (gb1 >= N) gb1 = N - 1;
    const f16* pa0 = A + (long)ga0 * K + k80 * 8;
    const f16* pa1 = A + (long)ga1 * K + k81 * 8;
    const f16* pb0 = Bm + (long)gb0 * K + k80 * 8;
    const f16* pb1 = Bm + (long)gb1 * K + k81 * 8;
    for (int kt = 0; kt < K; kt += 32) {
        gld16(pa0 + kt, As + idxu * 8);
        gld16(pa1 + kt, As + idxu * 8 + 512);
        gld16(pb0 + kt, Bs + idxu * 8);
        gld16(pb1 + kt, Bs + idxu * 8 + 512);
        __syncthreads();                         // drains vmcnt -> tiles resident
        f16x8 af[4], bf[4];
#pragma unroll
        for (int m = 0; m < 4; ++m) af[m] = *(const f16x8*)(As + (wm * 64 + m * 16 + fr) * 32 + kg * 8);
#pragma unroll
        for (int n = 0; n < 4; ++n) bf[n] = *(const f16x8*)(Bs + (wn * 64 + n * 16 + fr) * 32 + kg * 8);
#pragma unroll
        for (int m = 0; m < 4; ++m)
#pragma unroll
            for (int n = 0; n < 4; ++n)
                acc[m][n] = __builtin_amdgcn_mfma_f32_16x16x32_f16(af[m], bf[n], acc[m][n], 0, 0, 0);
        __syncthreads();
    }
    const int crow = m0 + wm * 64 + (lane >> 4) * 4;
    const int ccol = n0 + wn * 64 + fr;
    if (MODE == 3) {
        float rs[4][4];
#pragma unroll
        for (int m = 0; m < 4; ++m)
#pragma unroll
            for (int q = 0; q < 4; ++q) rs[m][q] = 0.f;
#pragma unroll
        for (int n = 0; n < 4; ++n) {
            int col = ccol + n * 16;
            if (col >= N) continue;
#pragma unroll
            for (int m = 0; m < 4; ++m) {
#pragma unroll
                for (int q = 0; q < 4; ++q) {
                    int row = crow + m * 16 + q;
                    if (row < M) {
                        float e = __expf(acc[m][n][q]);
                        C[(long)row * N + col] = e;
                        rs[m][q] += e;
                    }
                }
            }
        }
#pragma unroll
        for (int m = 0; m < 4; ++m)
#pragma unroll
            for (int q = 0; q < 4; ++q) {
                float v = rs[m][q];
                v += __shfl_xor(v, 1);
                v += __shfl_xor(v, 2);
                v += __shfl_xor(v, 4);
                v += __shfl_xor(v, 8);
                rs[m][q] = v;
            }
        if ((lane & 15) == 0) {
#pragma unroll
            for (int m = 0; m < 4; ++m)
#pragma unroll
                for (int q = 0; q < 4; ++q)
                    rpart[wn][wm * 64 + (lane >> 4) * 4 + m * 16 + q] = rs[m][q];
        }
        __syncthreads();
        if (tid < 128) {
            int row = m0 + tid;
            if (row < M) psum[(long)blockIdx.x * M + row] = rpart[0][tid] + rpart[1][tid];
        }
    } else {
#pragma unroll
        for (int n = 0; n < 4; ++n) {
            int col = ccol + n * 16;
            if (col >= N) continue;
            float bv = (MODE == 1) ? bias[col] : 0.f;
#pragma unroll
            for (int m = 0; m < 4; ++m) {
#pragma unroll
                for (int q = 0; q < 4; ++q) {
                    int row = crow + m * 16 + q;
                    if (row < M) {
                        long idx = (long)row * N + col;
                        float v = acc[m][n][q] + bv;
                        if (MODE == 2) v += C[idx];
                        C[idx] = v;
                    }
                }
            }
        }
    }
}

// ---------------------------------------------------------------- GRU recurrence
// 192 blocks = 8 chains (one per batch) x 24 blocks x 32 units.
// f16 weights: LDS-staged then lifted to 144 VGPRs (R6-proven numerics).
// h exchange: seq-tagged ull via RELAXED agent atomics (R5-proven protocol);
// every block reads ALL 768 words of step s before writing s+1 -> 1-step
// spread bound -> parity double-buffer, no flags, no global barrier.
__device__ __forceinline__ float fd2(unsigned hv, unsigned wv, float acc) {
#if __has_builtin(__builtin_amdgcn_fdot2)
    return __builtin_amdgcn_fdot2(__builtin_bit_cast(h2, hv), __builtin_bit_cast(h2, wv), acc, false);
#else
    h2 a = __builtin_bit_cast(h2, hv), b = __builtin_bit_cast(h2, wv);
    return acc + (float)a.x * (float)b.x + (float)a.y * (float)b.y;
#endif
}

__global__ __launch_bounds__(256, 1) void k_gru(const float* __restrict__ gi,
                                                const f16* __restrict__ wh16,
                                                const float* __restrict__ bhh,
                                                ull* hbuf,
                                                f16* __restrict__ Hhi, f16* __restrict__ Hlo) {
    __shared__ ui4v wsvu[9216];               // [g][k8][u]: ((g*96+k8)*32+u), 147456 B
    __shared__ __align__(16) f16 hsf[768];
    __shared__ float hs32[768];
    __shared__ float part[8][32][3];
    const int tid = threadIdx.x;
    const int chain = blockIdx.x / CBLK;      // batch 0..7
    const int blk = blockIdx.x % CBLK;
    const int u0 = blk * CUPB;
    for (int idx = tid; idx < 9216; idx += 256) {
        int uu = idx & 31, k8 = (idx >> 5) % 96, g = idx / (96 * 32);
        wsvu[idx] = *(const ui4v*)(wh16 + (long)(g * H_ + u0 + uu) * H_ + k8 * 8);
    }
    float b_r = 0.f, b_z = 0.f, b_n = 0.f;
    if (tid < 32) {
        int c = u0 + tid;
        b_r = bhh[c];
        b_z = bhh[H_ + c];
        b_n = bhh[2 * H_ + c];
    }
    __syncthreads();
    const int u = tid & 31, q = tid >> 5;
    ui4v wreg[3][12];
#pragma unroll
    for (int g = 0; g < 3; ++g)
#pragma unroll
        for (int i = 0; i < 12; ++i)
            wreg[g][i] = wsvu[(g * 96 + q * 12 + i) * 32 + u];
    ull* base = hbuf + (long)chain * 1536;
    for (int s = 0; s < 270; ++s) {
        const ull* rb = base + (s & 1) * 768;
        ull* wb = base + ((s + 1) & 1) * 768;
        const unsigned want = (unsigned)s;
        ull v0, v1, v2;
        for (;;) {
            v0 = __hip_atomic_load(rb + tid, __ATOMIC_RELAXED, __HIP_MEMORY_SCOPE_AGENT);
            v1 = __hip_atomic_load(rb + tid + 256, __ATOMIC_RELAXED, __HIP_MEMORY_SCOPE_AGENT);
            v2 = __hip_atomic_load(rb + tid + 512, __ATOMIC_RELAXED, __HIP_MEMORY_SCOPE_AGENT);
            bool ok = ((unsigned)(v0 >> 32) == want) & ((unsigned)(v1 >> 32) == want) &
                      ((unsigned)(v2 >> 32) == want);
            if (ok) break;
        }
        float f0 = __uint_as_float((unsigned)v0);
        float f1 = __uint_as_float((unsigned)v1);
        float f2 = __uint_as_float((unsigned)v2);
        hs32[tid] = f0;         hsf[tid] = (f16)f0;
        hs32[tid + 256] = f1;   hsf[tid + 256] = (f16)f1;
        hs32[tid + 512] = f2;   hsf[tid + 512] = (f16)f2;
        __syncthreads();                       // A: h_s staged
        float hold = 0.f, g0 = 0.f, g1 = 0.f, g2v = 0.f;
        if (tid < 32) {
            int c = u0 + tid;
            hold = hs32[c];
            const float* gp = gi + ((long)chain * 270 + s) * H3;
            g0 = gp[c];
            g1 = gp[H_ + c];
            g2v = gp[2 * H_ + c];
        }
        float ar = 0.f, az = 0.f, an = 0.f;
#pragma unroll
        for (int i = 0; i < 12; ++i) {
            ui4v hv = *(const ui4v*)(&hsf[(q * 12 + i) * 8]);
            ui4v wr = wreg[0][i], wz = wreg[1][i], wn = wreg[2][i];
            ar = fd2(hv.x, wr.x, ar); ar = fd2(hv.y, wr.y, ar);
            ar = fd2(hv.z, wr.z, ar); ar = fd2(hv.w, wr.w, ar);
            az = fd2(hv.x, wz.x, az); az = fd2(hv.y, wz.y, az);
            az = fd2(hv.z, wz.z, az); az = fd2(hv.w, wz.w, az);
            an = fd2(hv.x, wn.x, an); an = fd2(hv.y, wn.y, an);
            an = fd2(hv.z, wn.z, an); an = fd2(hv.w, wn.w, an);
        }
        part[q][u][0] = ar;
        part[q][u][1] = az;
        part[q][u][2] = an;
        __syncthreads();                       // B: partials ready; hsf reads done
        if (tid < 32) {
            float gr = b_r, gz = b_z, gn = b_n;
#pragma unroll
            for (int qq = 0; qq < 8; ++qq) {
                gr += part[qq][tid][0];
                gz += part[qq][tid][1];
                gn += part[qq][tid][2];
            }
            float rg = 1.f / (1.f + expf(-(g0 + gr)));
            float zg = 1.f / (1.f + expf(-(g1 + gz)));
            float ng = tanhf(g2v + rg * gn);
            float hnew = (1.f - zg) * ng + zg * hold;
            int c = u0 + tid;
            ull wv = ((ull)(unsigned)(s + 1) << 32) | (ull)__float_as_uint(hnew);
            __hip_atomic_store(wb + c, wv, __ATOMIC_RELAXED, __HIP_MEMORY_SCOPE_AGENT);
            long row = (long)chain * 270 + s;
            f16 hi16 = (f16)hnew;
            Hhi[row * H_ + c] = hi16;
            Hlo[row * H_ + c] = (f16)(hnew - (float)hi16);
        }
        // no end barrier: next-step staging is gated by barrier B + the poll
    }
}

// ---------------------------------------------------------------- attention softmax
__global__ __launch_bounds__(256) void k_attn_softmax(const float* __restrict__ lg,
                                                      const int* __restrict__ x, f16* __restrict__ ah) {
    __shared__ float red[256];
    int r = blockIdx.x, tid = threadIdx.x;
    int b = r / 270;
    const float* lr = lg + (long)r * S_;
    const int* xb = x + (long)b * S_;
    float v0 = lr[tid];
    if (xb[tid] == 0) v0 = -1e9f;
    float v1 = lr[tid + 256];
    if (xb[tid + 256] == 0) v1 = -1e9f;
    red[tid] = fmaxf(v0, v1);
    __syncthreads();
    for (int o = 128; o > 0; o >>= 1) {
        if (tid < o) red[tid] = fmaxf(red[tid], red[tid + o]);
        __syncthreads();
    }
    float m = red[0];
    __syncthreads();
    float e0 = __expf(v0 - m), e1 = __expf(v1 - m);
    red[tid] = e0 + e1;
    __syncthreads();
    for (int o = 128; o > 0; o >>= 1) {
        if (tid < o) red[tid] += red[tid + o];
        __syncthreads();
    }
    float inv = 1.f / red[0];
    ah[(long)r * S_ + tid] = (f16)(e0 * inv);
    ah[(long)r * S_ + tid + 256] = (f16)(e1 * inv);
}

// ---------------------------------------------------------------- p_gen
__global__ __launch_bounds__(256) void k_pgen(const f16* __restrict__ Wall, const f16* __restrict__ Hhi,
                                              const f16* __restrict__ Hlo, const float* __restrict__ ctx,
                                              const float* __restrict__ wg, const float* __restrict__ wgb,
                                              float* __restrict__ pg) {
    __shared__ float red[256];
    int r = blockIdx.x, tid = threadIdx.x;
    float a = 0.f;
    for (int i = tid; i < H_; i += 256) {
        a += (float)Wall[(long)r * H_ + i] * wg[i];
        a += ((float)Hhi[(long)r * H_ + i] + (float)Hlo[(long)r * H_ + i]) * wg[H_ + i];
        a += ctx[(long)r * H_ + i] * wg[2 * H_ + i];
    }
    red[tid] = a;
    __syncthreads();
    for (int o = 128; o > 0; o >>= 1) {
        if (tid < o) red[tid] += red[tid + o];
        __syncthreads();
    }
    if (tid == 0) pg[r] = 1.f / (1.f + expf(-(red[0] + wgb[0])));
}

// ---------------------------------------------------------------- rowsum reduce: rinv = 1/sum_b psum[b][r]
__global__ void k_redsum(const float* __restrict__ psum, float* __restrict__ rinv, int nb) {
    int r = blockIdx.x * 256 + threadIdx.x;
    if (r >= R_) return;
    float s = 0.f;
    for (int b = 0; b < nb; ++b) s += psum[(long)b * R_ + r];
    rinv[r] = 1.f / s;
}

// ---------------------------------------------------------------- finalize: out = pg * exp * rinv (in place)
__global__ __launch_bounds__(256) void k_final(float* __restrict__ out, const float* __restrict__ rinv,
                                               const float* __restrict__ pg) {
    int r = blockIdx.y;
    int i = blockIdx.x * 256 + threadIdx.x;
    if (i >= V_ / 4) return;
    float scale = pg[r] * rinv[r];
    f32x4* po = (f32x4*)(out + (long)r * V_);
    f32x4 v = po[i];
    v.x *= scale;
    v.y *= scale;
    v.z *= scale;
    v.w *= scale;
    po[i] = v;
}

// ---------------------------------------------------------------- pointer scatter
__global__ __launch_bounds__(512) void k_scatter(float* __restrict__ out, const f16* __restrict__ ah,
                                                 const float* __restrict__ pg, const int* __restrict__ x) {
    int r = blockIdx.x, s = threadIdx.x;
    int b = r / 270;
    int xv = x[(long)b * S_ + s];
    if (xv == 0) return;
    float a = (float)ah[(long)r * S_ + s];
    if (a == 0.f) return;
    atomicAdd(out + (long)r * V_ + xv, (1.f - pg[r]) * a);
}

// ---------------------------------------------------------------- host
extern "C" void kernel_launch(void* const* d_in, const int* in_sizes, int n_in, void* d_out,
                              int out_size, void* d_ws, size_t ws_size, hipStream_t stream) {
    (void)in_sizes; (void)n_in; (void)out_size; (void)ws_size;
    const int* x = (const int*)d_in[0];
    const float* dec = (const float*)d_in[1];
    const float* enc = (const float*)d_in[2];
    const float* hid = (const float*)d_in[3];
    const int* tea = (const int*)d_in[4];
    const float* emb = (const float*)d_in[6];
    const float* wih = (const float*)d_in[7];
    const float* whh = (const float*)d_in[8];
    const float* bih = (const float*)d_in[9];
    const float* bhh = (const float*)d_in[10];
    const float* wgw = (const float*)d_in[11];
    const float* wgb = (const float*)d_in[12];
    float* out = (float*)d_out;

    char* w = (char*)d_ws;
    size_t off = 0;
    auto alloc = [&](size_t bytes) {
        void* p = w + off;
        off = (off + bytes + 255) & ~(size_t)255;
        return p;
    };
    ull* hbuf = (ull*)alloc(8 * 1536 * 8);          // [chain][parity][768] seq-tagged h
    f16* Wall = (f16*)alloc((size_t)R_ * H_ * 2);
    f16* wih16 = (f16*)alloc((size_t)H3 * H_ * 2);
    f16* wh16 = (f16*)alloc((size_t)H3 * H_ * 2);
    float* giA = (float*)alloc((size_t)R_ * H3 * 4);
    f16* Hhi = (f16*)alloc((size_t)R_ * H_ * 2);
    f16* Hlo = (f16*)alloc((size_t)R_ * H_ * 2);
    f16* emb16 = (f16*)alloc((size_t)V_ * H_ * 2);
    f16* ehi = (f16*)alloc((size_t)B_ * S_ * H_ * 2);
    f16* elo = (f16*)alloc((size_t)B_ * S_ * H_ * 2);
    f16* encT = (f16*)alloc((size_t)B_ * H_ * S_ * 2);
    float* lgH = (float*)alloc((size_t)R_ * S_ * 4);
    f16* ah = (f16*)alloc((size_t)R_ * S_ * 2);
    float* ctx = (float*)alloc((size_t)R_ * H_ * 4);
    float* pg = (float*)alloc(R_ * 4);
    float* psum = (float*)alloc((size_t)274 * R_ * 4);
    float* rinv = (float*)alloc(R_ * 4);

    const int nH = 8 * 1536 * 2;                    // hbuf as ints
    k_zero<<<(nH + 255) / 256, 256, 0, stream>>>((int*)hbuf, nH);
    k_cast<<<2048, 256, 0, stream>>>(emb, emb16, (long)V_ * H_);
    k_cast<<<512, 256, 0, stream>>>(wih, wih16, (long)H3 * H_);
    k_cast<<<512, 256, 0, stream>>>(whh, wh16, (long)H3 * H_);
    k_build_wall<<<R_, 256, 0, stream>>>(emb, dec, tea, Wall);
    k_build_enc<<<1024, 256, 0, stream>>>(enc, ehi, elo, encT);
    k_init_h<<<24, 256, 0, stream>>>(hid, hbuf);

    // gi = W_all @ w_ih^T + b_ih
    {
        dim3 g(H3 / 128, (R_ + 127) / 128, 1);
        k_gemm<1><<<g, 256, 0, stream>>>(Wall, wih16, giA, bih, R_, H3, H_, 0, 0, 0, nullptr);
    }
    k_gru<<<8 * CBLK, 256, 0, stream>>>(giA, wh16, bhh, hbuf, Hhi, Hlo);

    // attention logits, hi/lo split: Hhi*Ehi + Hhi*Elo + Hlo*Ehi
    {
        dim3 g(S_ / 128, 3, 8);
        k_gemm<0><<<g, 256, 0, stream>>>(Hhi, ehi, lgH, nullptr, 270, S_, H_, 270L * H_, (long)S_ * H_, 270L * S_, nullptr);
        k_gemm<2><<<g, 256, 0, stream>>>(Hhi, elo, lgH, nullptr, 270, S_, H_, 270L * H_, (long)S_ * H_, 270L * S_, nullptr);
        k_gemm<2><<<g, 256, 0, stream>>>(Hlo, ehi, lgH, nullptr, 270, S_, H_, 270L * H_, (long)S_ * H_, 270L * S_, nullptr);
    }
    k_attn_softmax<<<R_, 256, 0, stream>>>(lgH, x, ah);
    {
        dim3 g(H_ / 128, 3, 8);
        k_gemm<0><<<g, 256, 0, stream>>>(ah, encT, ctx, nullptr, 270, H_, S_, 270L * S_, (long)H_ * S_, 270L * H_, nullptr);
    }
    k_pgen<<<R_, 256, 0, stream>>>(Wall, Hhi, Hlo, ctx, wgw, wgb, pg);

    // vocab: out = exp(Hhi @ emb16^T), row partial sums -> psum
    {
        dim3 g((V_ + 127) / 128, (R_ + 127) / 128, 1);
        k_gemm<3><<<g, 256, 0, stream>>>(Hhi, emb16, out, nullptr, R_, V_, H_, 0, 0, 0, psum);
    }
    k_redsum<<<(R_ + 255) / 256, 256, 0, stream>>>(psum, rinv, (V_ + 127) / 128);
    {
        dim3 g((V_ / 4 + 255) / 256, R_, 1);
        k_final<<<g, 256, 0, stream>>>(out, rinv, pg);
    }
    k_scatter<<<R_, 512, 0, stream>>>(out, ah, pg, x);
}

// Round 9
// 1151.942 us; speedup vs baseline: 1.9143x; 1.0598x over previous
//
#include <hip/hip_runtime.h>
#include <hip/hip_bf16.h>

typedef _Float16 f16;
typedef _Float16 f16x8 __attribute__((ext_vector_type(8)));
typedef _Float16 h2 __attribute__((ext_vector_type(2)));
typedef float f32x4 __attribute__((ext_vector_type(4)));
typedef unsigned ui4v __attribute__((ext_vector_type(4)));
typedef unsigned long long ull;

#define B_ 8
#define S_ 512
#define H_ 768
#define V_ 35004
#define J_ 30
#define K_ 9
#define R_ 2160          // B*J*K rows, row r = b*270 + j*9 + t  (matches out layout)
#define H3 2304
#define CBLK 24          // blocks per chain (one chain = one batch)
#define CUPB 32          // hidden units per block
#define VMT 17           // vocab M tiles
#define VNT 274          // vocab N tiles

// ---------------------------------------------------------------- prep kernels

__global__ void k_zero(int* p, int n) {
    int i = blockIdx.x * 256 + threadIdx.x;
    if (i < n) p[i] = 0;
}

__global__ void k_cast(const float* __restrict__ s, f16* __restrict__ d, long n) {
    for (long i = (long)blockIdx.x * 256 + threadIdx.x; i < n; i += (long)gridDim.x * 256)
        d[i] = (f16)s[i];
}

// W_all[r] = (t==0) ? decoder_input[b,j,:] : embed[teacher[b,j,t-1],:]
__global__ void k_build_wall(const float* __restrict__ emb, const float* __restrict__ dec,
                             const int* __restrict__ teacher, f16* __restrict__ Wall) {
    int r = blockIdx.x;
    int b = r / 270, s = r % 270, j = s / 9, t = s % 9;
    const float* src = (t == 0) ? dec + ((long)b * J_ + j) * H_
                                : emb + (long)teacher[((long)b * J_ + j) * K_ + (t - 1)] * H_;
    f16* dst = Wall + (long)r * H_;
    for (int c = threadIdx.x; c < H_; c += 256) dst[c] = (f16)src[c];
}

// enc hi/lo split (row-major [b][s][h]) + encT hi ([b][h][s]) for context GEMM
__global__ void k_build_enc(const float* __restrict__ enc, f16* __restrict__ ehi,
                            f16* __restrict__ elo, f16* __restrict__ encT) {
    long n = (long)B_ * S_ * H_;
    for (long i = (long)blockIdx.x * 256 + threadIdx.x; i < n; i += (long)gridDim.x * 256) {
        float v = enc[i];
        f16 hi = (f16)v;
        ehi[i] = hi;
        elo[i] = (f16)(v - (float)hi);
        int h = (int)(i % H_);
        long bs = i / H_;
        int s = (int)(bs % S_), b = (int)(bs / S_);
        encT[((long)b * H_ + h) * S_ + s] = hi;
    }
}

// h exchange word: {seq:32 | f32 bits:32}; chain-major [chain][parity][768]
__global__ void k_init_h(const float* __restrict__ hidden, ull* __restrict__ hbuf) {
    int i = blockIdx.x * 256 + threadIdx.x;
    if (i < B_ * H_) {
        int b = i / H_, u = i % H_;
        hbuf[(long)b * 1536 + u] = (ull)__float_as_uint(hidden[i]);  // seq 0, parity 0
    }
}

// ---------------------------------------------------------------- shared GEMM helpers
typedef const __attribute__((address_space(1))) unsigned GASU;
typedef __attribute__((address_space(3))) unsigned LASU;
__device__ __forceinline__ void gld16(const f16* g, f16* l) {
    __builtin_amdgcn_global_load_lds((GASU*)g, (LASU*)l, 16, 0, 0);
}

// ---------------------------------------------------------------- f16 MFMA GEMM (m97 structure)
// C[M,N] = A[M,K] @ B[N,K]^T ; MODE 0: store, 1: store + bias[col]
template <int MODE>
__global__ __launch_bounds__(256) void k_gemm(const f16* __restrict__ A, const f16* __restrict__ Bm,
                                              float* __restrict__ C, const float* __restrict__ bias,
                                              int M, int N, int K, long sA, long sB, long sC) {
    A += (long)blockIdx.z * sA;
    Bm += (long)blockIdx.z * sB;
    C += (long)blockIdx.z * sC;
    const int m0 = blockIdx.y * 128, n0 = blockIdx.x * 128;
    __shared__ f16 As[128 * 32];
    __shared__ f16 Bs[128 * 32];
    const int tid = threadIdx.x, lane = tid & 63, wave = tid >> 6;
    const int wm = wave >> 1, wn = wave & 1;
    const int fr = lane & 15, kg = lane >> 4;
    f32x4 acc[4][4] = {};
    const int idxu = wave * 128;
    const int i0 = idxu + lane, i1 = idxu + 64 + lane;
    const int r0 = i0 >> 2, k80 = i0 & 3;
    const int r1 = i1 >> 2, k81 = i1 & 3;
    int ga0 = m0 + r0; if (ga0 >= M) ga0 = M - 1;
    int ga1 = m0 + r1; if (ga1 >= M) ga1 = M - 1;
    int gb0 = n0 + r0; if (gb0 >= N) gb0 = N - 1;
    int gb1 = n0 + r1; if (gb1 >= N) gb1 = N - 1;
    const f16* pa0 = A + (long)ga0 * K + k80 * 8;
    const f16* pa1 = A + (long)ga1 * K + k81 * 8;
    const f16* pb0 = Bm + (long)gb0 * K + k80 * 8;
    const f16* pb1 = Bm + (long)gb1 * K + k81 * 8;
    for (int kt = 0; kt < K; kt += 32) {
        gld16(pa0 + kt, As + idxu * 8);
        gld16(pa1 + kt, As + idxu * 8 + 512);
        gld16(pb0 + kt, Bs + idxu * 8);
        gld16(pb1 + kt, Bs + idxu * 8 + 512);
        __syncthreads();
        f16x8 af[4], bf[4];
#pragma unroll
        for (int m = 0; m < 4; ++m) af[m] = *(const f16x8*)(As + (wm * 64 + m * 16 + fr) * 32 + kg * 8);
#pragma unroll
        for (int n = 0; n < 4; ++n) bf[n] = *(const f16x8*)(Bs + (wn * 64 + n * 16 + fr) * 32 + kg * 8);
#pragma unroll
        for (int m = 0; m < 4; ++m)
#pragma unroll
            for (int n = 0; n < 4; ++n)
                acc[m][n] = __builtin_amdgcn_mfma_f32_16x16x32_f16(af[m], bf[n], acc[m][n], 0, 0, 0);
        __syncthreads();
    }
    const int crow = m0 + wm * 64 + (lane >> 4) * 4;
    const int ccol = n0 + wn * 64 + fr;
#pragma unroll
    for (int n = 0; n < 4; ++n) {
        int col = ccol + n * 16;
        if (col >= N) continue;
        float bv = (MODE == 1) ? bias[col] : 0.f;
#pragma unroll
        for (int m = 0; m < 4; ++m) {
#pragma unroll
            for (int q = 0; q < 4; ++q) {
                int row = crow + m * 16 + q;
                if (row < M) C[(long)row * N + col] = acc[m][n][q] + bv;
            }
        }
    }
}

// ---------------------------------------------------------------- merged hi/lo attention logits
// C = Ahi@Bhi^T + Ahi@Blo^T + Alo@Bhi^T  (one launch, shared accumulator)
__global__ __launch_bounds__(256) void k_attn3(const f16* __restrict__ Ahi, const f16* __restrict__ Alo,
                                               const f16* __restrict__ Bhi, const f16* __restrict__ Blo,
                                               float* __restrict__ C, int M, int N, int K,
                                               long sA, long sB, long sC) {
    const long za = (long)blockIdx.z * sA, zb = (long)blockIdx.z * sB;
    C += (long)blockIdx.z * sC;
    const int m0 = blockIdx.y * 128, n0 = blockIdx.x * 128;
    __shared__ f16 As[128 * 32];
    __shared__ f16 Bs[128 * 32];
    const int tid = threadIdx.x, lane = tid & 63, wave = tid >> 6;
    const int wm = wave >> 1, wn = wave & 1;
    const int fr = lane & 15, kg = lane >> 4;
    f32x4 acc[4][4] = {};
    const int idxu = wave * 128;
    const int i0 = idxu + lane, i1 = idxu + 64 + lane;
    const int r0 = i0 >> 2, k80 = i0 & 3;
    const int r1 = i1 >> 2, k81 = i1 & 3;
    int ga0 = m0 + r0; if (ga0 >= M) ga0 = M - 1;
    int ga1 = m0 + r1; if (ga1 >= M) ga1 = M - 1;
    int gb0 = n0 + r0; if (gb0 >= N) gb0 = N - 1;
    int gb1 = n0 + r1; if (gb1 >= N) gb1 = N - 1;
    const long oa0 = (long)ga0 * K + k80 * 8, oa1 = (long)ga1 * K + k81 * 8;
    const long ob0 = (long)gb0 * K + k80 * 8, ob1 = (long)gb1 * K + k81 * 8;
    for (int ph = 0; ph < 3; ++ph) {
        const f16* Ap = (ph == 2 ? Alo : Ahi) + za;
        const f16* Bp = (ph == 1 ? Blo : Bhi) + zb;
        for (int kt = 0; kt < K; kt += 32) {
            gld16(Ap + oa0 + kt, As + idxu * 8);
            gld16(Ap + oa1 + kt, As + idxu * 8 + 512);
            gld16(Bp + ob0 + kt, Bs + idxu * 8);
            gld16(Bp + ob1 + kt, Bs + idxu * 8 + 512);
            __syncthreads();
            f16x8 af[4], bf[4];
#pragma unroll
            for (int m = 0; m < 4; ++m) af[m] = *(const f16x8*)(As + (wm * 64 + m * 16 + fr) * 32 + kg * 8);
#pragma unroll
            for (int n = 0; n < 4; ++n) bf[n] = *(const f16x8*)(Bs + (wn * 64 + n * 16 + fr) * 32 + kg * 8);
#pragma unroll
            for (int m = 0; m < 4; ++m)
#pragma unroll
                for (int n = 0; n < 4; ++n)
                    acc[m][n] = __builtin_amdgcn_mfma_f32_16x16x32_f16(af[m], bf[n], acc[m][n], 0, 0, 0);
            __syncthreads();
        }
    }
    const int crow = m0 + wm * 64 + (lane >> 4) * 4;
    const int ccol = n0 + wn * 64 + fr;
#pragma unroll
    for (int n = 0; n < 4; ++n) {
        int col = ccol + n * 16;
        if (col >= N) continue;
#pragma unroll
        for (int m = 0; m < 4; ++m) {
#pragma unroll
            for (int q = 0; q < 4; ++q) {
                int row = crow + m * 16 + q;
                if (row < M) C[(long)row * N + col] = acc[m][n][q];
            }
        }
    }
}

// ---------------------------------------------------------------- vocab GEMM: out=exp(Hhi@emb^T), psum
// 1D grid, M-innermost + bijective XCD-chunked swizzle: each XCD owns a
// contiguous run of N-panels -> emb16 panel fetched into ONE L2, reused by all
// 17 M-tiles (kills the 912 MB L3 refetch of the N-major grid).
__global__ __launch_bounds__(256) void k_vocab(const f16* __restrict__ A, const f16* __restrict__ Bm,
                                               float* __restrict__ C, float* __restrict__ psum) {
    const int M = R_, N = V_, K = H_;
    const int nwg = VMT * VNT;
    int lin = blockIdx.x;
    int q8 = nwg / 8, r8 = nwg % 8;
    int xcd = lin & 7, idx = lin >> 3;
    int newlin = (xcd < r8) ? xcd * (q8 + 1) + idx : r8 * (q8 + 1) + (xcd - r8) * q8 + idx;
    int mt = newlin % VMT, nt = newlin / VMT;
    const int m0 = mt * 128, n0 = nt * 128;
    __shared__ f16 As[128 * 32];
    __shared__ f16 Bs[128 * 32];
    __shared__ float rpart[2][128];
    const int tid = threadIdx.x, lane = tid & 63, wave = tid >> 6;
    const int wm = wave >> 1, wn = wave & 1;
    const int fr = lane & 15, kg = lane >> 4;
    f32x4 acc[4][4] = {};
    const int idxu = wave * 128;
    const int i0 = idxu + lane, i1 = idxu + 64 + lane;
    const int r0 = i0 >> 2, k80 = i0 & 3;
    const int r1 = i1 >> 2, k81 = i1 & 3;
    int ga0 = m0 + r0; if (ga0 >= M) ga0 = M - 1;
    int ga1 = m0 + r1; if (ga1 >= M) ga1 = M - 1;
    int gb0 = n0 + r0; if (gb0 >= N) gb0 = N - 1;
    int gb1 = n0 + r1; if (gb1 >= N) gb1 = N - 1;
    const f16* pa0 = A + (long)ga0 * K + k80 * 8;
    const f16* pa1 = A + (long)ga1 * K + k81 * 8;
    const f16* pb0 = Bm + (long)gb0 * K + k80 * 8;
    const f16* pb1 = Bm + (long)gb1 * K + k81 * 8;
    for (int kt = 0; kt < K; kt += 32) {
        gld16(pa0 + kt, As + idxu * 8);
        gld16(pa1 + kt, As + idxu * 8 + 512);
        gld16(pb0 + kt, Bs + idxu * 8);
        gld16(pb1 + kt, Bs + idxu * 8 + 512);
        __syncthreads();
        f16x8 af[4], bf[4];
#pragma unroll
        for (int m = 0; m < 4; ++m) af[m] = *(const f16x8*)(As + (wm * 64 + m * 16 + fr) * 32 + kg * 8);
#pragma unroll
        for (int n = 0; n < 4; ++n) bf[n] = *(const f16x8*)(Bs + (wn * 64 + n * 16 + fr) * 32 + kg * 8);
#pragma unroll
        for (int m = 0; m < 4; ++m)
#pragma unroll
            for (int n = 0; n < 4; ++n)
                acc[m][n] = __builtin_amdgcn_mfma_f32_16x16x32_f16(af[m], bf[n], acc[m][n], 0, 0, 0);
        __syncthreads();
    }
    const int crow = m0 + wm * 64 + (lane >> 4) * 4;
    const int ccol = n0 + wn * 64 + fr;
    float rs[4][4];
#pragma unroll
    for (int m = 0; m < 4; ++m)
#pragma unroll
        for (int q = 0; q < 4; ++q) rs[m][q] = 0.f;
#pragma unroll
    for (int n = 0; n < 4; ++n) {
        int col = ccol + n * 16;
        if (col >= N) continue;
#pragma unroll
        for (int m = 0; m < 4; ++m) {
#pragma unroll
            for (int q = 0; q < 4; ++q) {
                int row = crow + m * 16 + q;
                if (row < M) {
                    float e = __expf(acc[m][n][q]);
                    C[(long)row * N + col] = e;
                    rs[m][q] += e;
                }
            }
        }
    }
#pragma unroll
    for (int m = 0; m < 4; ++m)
#pragma unroll
        for (int q = 0; q < 4; ++q) {
            float v = rs[m][q];
            v += __shfl_xor(v, 1);
            v += __shfl_xor(v, 2);
            v += __shfl_xor(v, 4);
            v += __shfl_xor(v, 8);
            rs[m][q] = v;
        }
    if ((lane & 15) == 0) {
#pragma unroll
        for (int m = 0; m < 4; ++m)
#pragma unroll
            for (int q = 0; q < 4; ++q)
                rpart[wn][wm * 64 + (lane >> 4) * 4 + m * 16 + q] = rs[m][q];
    }
    __syncthreads();
    if (tid < 128) {
        int row = m0 + tid;
        if (row < M) psum[(long)nt * M + row] = rpart[0][tid] + rpart[1][tid];
    }
}

// ---------------------------------------------------------------- GRU recurrence (R8, proven)
__device__ __forceinline__ float fd2(unsigned hv, unsigned wv, float acc) {
#if __has_builtin(__builtin_amdgcn_fdot2)
    return __builtin_amdgcn_fdot2(__builtin_bit_cast(h2, hv), __builtin_bit_cast(h2, wv), acc, false);
#else
    h2 a = __builtin_bit_cast(h2, hv), b = __builtin_bit_cast(h2, wv);
    return acc + (float)a.x * (float)b.x + (float)a.y * (float)b.y;
#endif
}

__global__ __launch_bounds__(256, 1) void k_gru(const float* __restrict__ gi,
                                                const f16* __restrict__ wh16,
                                                const float* __restrict__ bhh,
                                                ull* hbuf,
                                                f16* __restrict__ Hhi, f16* __restrict__ Hlo) {
    __shared__ ui4v wsvu[9216];               // [g][k8][u]: ((g*96+k8)*32+u), 147456 B
    __shared__ __align__(16) f16 hsf[768];
    __shared__ float hs32[768];
    __shared__ float part[8][32][3];
    const int tid = threadIdx.x;
    const int chain = blockIdx.x / CBLK;      // batch 0..7
    const int blk = blockIdx.x % CBLK;
    const int u0 = blk * CUPB;
    for (int idx = tid; idx < 9216; idx += 256) {
        int uu = idx & 31, k8 = (idx >> 5) % 96, g = idx / (96 * 32);
        wsvu[idx] = *(const ui4v*)(wh16 + (long)(g * H_ + u0 + uu) * H_ + k8 * 8);
    }
    float b_r = 0.f, b_z = 0.f, b_n = 0.f;
    if (tid < 32) {
        int c = u0 + tid;
        b_r = bhh[c];
        b_z = bhh[H_ + c];
        b_n = bhh[2 * H_ + c];
    }
    __syncthreads();
    const int u = tid & 31, q = tid >> 5;
    ui4v wreg[3][12];
#pragma unroll
    for (int g = 0; g < 3; ++g)
#pragma unroll
        for (int i = 0; i < 12; ++i)
            wreg[g][i] = wsvu[(g * 96 + q * 12 + i) * 32 + u];
    ull* base = hbuf + (long)chain * 1536;
    for (int s = 0; s < 270; ++s) {
        const ull* rb = base + (s & 1) * 768;
        ull* wb = base + ((s + 1) & 1) * 768;
        const unsigned want = (unsigned)s;
        ull v0, v1, v2;
        for (;;) {
            v0 = __hip_atomic_load(rb + tid, __ATOMIC_RELAXED, __HIP_MEMORY_SCOPE_AGENT);
            v1 = __hip_atomic_load(rb + tid + 256, __ATOMIC_RELAXED, __HIP_MEMORY_SCOPE_AGENT);
            v2 = __hip_atomic_load(rb + tid + 512, __ATOMIC_RELAXED, __HIP_MEMORY_SCOPE_AGENT);
            bool ok = ((unsigned)(v0 >> 32) == want) & ((unsigned)(v1 >> 32) == want) &
                      ((unsigned)(v2 >> 32) == want);
            if (ok) break;
        }
        float f0 = __uint_as_float((unsigned)v0);
        float f1 = __uint_as_float((unsigned)v1);
        float f2 = __uint_as_float((unsigned)v2);
        hs32[tid] = f0;         hsf[tid] = (f16)f0;
        hs32[tid + 256] = f1;   hsf[tid + 256] = (f16)f1;
        hs32[tid + 512] = f2;   hsf[tid + 512] = (f16)f2;
        __syncthreads();                       // A: h_s staged
        float hold = 0.f, g0 = 0.f, g1 = 0.f, g2v = 0.f;
        if (tid < 32) {
            int c = u0 + tid;
            hold = hs32[c];
            const float* gp = gi + ((long)chain * 270 + s) * H3;
            g0 = gp[c];
            g1 = gp[H_ + c];
            g2v = gp[2 * H_ + c];
        }
        float ar = 0.f, az = 0.f, an = 0.f;
#pragma unroll
        for (int i = 0; i < 12; ++i) {
            ui4v hv = *(const ui4v*)(&hsf[(q * 12 + i) * 8]);
            ui4v wr = wreg[0][i], wz = wreg[1][i], wn = wreg[2][i];
            ar = fd2(hv.x, wr.x, ar); ar = fd2(hv.y, wr.y, ar);
            ar = fd2(hv.z, wr.z, ar); ar = fd2(hv.w, wr.w, ar);
            az = fd2(hv.x, wz.x, az); az = fd2(hv.y, wz.y, az);
            az = fd2(hv.z, wz.z, az); az = fd2(hv.w, wz.w, az);
            an = fd2(hv.x, wn.x, an); an = fd2(hv.y, wn.y, an);
            an = fd2(hv.z, wn.z, an); an = fd2(hv.w, wn.w, an);
        }
        part[q][u][0] = ar;
        part[q][u][1] = az;
        part[q][u][2] = an;
        __syncthreads();                       // B: partials ready; hsf reads done
        if (tid < 32) {
            float gr = b_r, gz = b_z, gn = b_n;
#pragma unroll
            for (int qq = 0; qq < 8; ++qq) {
                gr += part[qq][tid][0];
                gz += part[qq][tid][1];
                gn += part[qq][tid][2];
            }
            float rg = 1.f / (1.f + expf(-(g0 + gr)));
            float zg = 1.f / (1.f + expf(-(g1 + gz)));
            float ng = tanhf(g2v + rg * gn);
            float hnew = (1.f - zg) * ng + zg * hold;
            int c = u0 + tid;
            ull wv = ((ull)(unsigned)(s + 1) << 32) | (ull)__float_as_uint(hnew);
            __hip_atomic_store(wb + c, wv, __ATOMIC_RELAXED, __HIP_MEMORY_SCOPE_AGENT);
            long row = (long)chain * 270 + s;
            f16 hi16 = (f16)hnew;
            Hhi[row * H_ + c] = hi16;
            Hlo[row * H_ + c] = (f16)(hnew - (float)hi16);
        }
        // no end barrier: next-step staging is gated by barrier B + the poll
    }
}

// ---------------------------------------------------------------- attention softmax
__global__ __launch_bounds__(256) void k_attn_softmax(const float* __restrict__ lg,
                                                      const int* __restrict__ x, f16* __restrict__ ah) {
    __shared__ float red[256];
    int r = blockIdx.x, tid = threadIdx.x;
    int b = r / 270;
    const float* lr = lg + (long)r * S_;
    const int* xb = x + (long)b * S_;
    float v0 = lr[tid];
    if (xb[tid] == 0) v0 = -1e9f;
    float v1 = lr[tid + 256];
    if (xb[tid + 256] == 0) v1 = -1e9f;
    red[tid] = fmaxf(v0, v1);
    __syncthreads();
    for (int o = 128; o > 0; o >>= 1) {
        if (tid < o) red[tid] = fmaxf(red[tid], red[tid + o]);
        __syncthreads();
    }
    float m = red[0];
    __syncthreads();
    float e0 = __expf(v0 - m), e1 = __expf(v1 - m);
    red[tid] = e0 + e1;
    __syncthreads();
    for (int o = 128; o > 0; o >>= 1) {
        if (tid < o) red[tid] += red[tid + o];
        __syncthreads();
    }
    float inv = 1.f / red[0];
    ah[(long)r * S_ + tid] = (f16)(e0 * inv);
    ah[(long)r * S_ + tid + 256] = (f16)(e1 * inv);
}

// ---------------------------------------------------------------- p_gen
__global__ __launch_bounds__(256) void k_pgen(const f16* __restrict__ Wall, const f16* __restrict__ Hhi,
                                              const f16* __restrict__ Hlo, const float* __restrict__ ctx,
                                              const float* __restrict__ wg, const float* __restrict__ wgb,
                                              float* __restrict__ pg) {
    __shared__ float red[256];
    int r = blockIdx.x, tid = threadIdx.x;
    float a = 0.f;
    for (int i = tid; i < H_; i += 256) {
        a += (float)Wall[(long)r * H_ + i] * wg[i];
        a += ((float)Hhi[(long)r * H_ + i] + (float)Hlo[(long)r * H_ + i]) * wg[H_ + i];
        a += ctx[(long)r * H_ + i] * wg[2 * H_ + i];
    }
    red[tid] = a;
    __syncthreads();
    for (int o = 128; o > 0; o >>= 1) {
        if (tid < o) red[tid] += red[tid + o];
        __syncthreads();
    }
    if (tid == 0) pg[r] = 1.f / (1.f + expf(-(red[0] + wgb[0])));
}

// ---------------------------------------------------------------- rowsum reduce: rinv = 1/sum_b psum[b][r]
__global__ void k_redsum(const float* __restrict__ psum, float* __restrict__ rinv, int nb) {
    int r = blockIdx.x * 256 + threadIdx.x;
    if (r >= R_) return;
    float s = 0.f;
    for (int b = 0; b < nb; ++b) s += psum[(long)b * R_ + r];
    rinv[r] = 1.f / s;
}

// ---------------------------------------------------------------- finalize: out = pg * exp * rinv (in place)
__global__ __launch_bounds__(256) void k_final(float* __restrict__ out, const float* __restrict__ rinv,
                                               const float* __restrict__ pg) {
    int r = blockIdx.y;
    int i = blockIdx.x * 256 + threadIdx.x;
    if (i >= V_ / 4) return;
    float scale = pg[r] * rinv[r];
    f32x4* po = (f32x4*)(out + (long)r * V_);
    f32x4 v = po[i];
    v.x *= scale;
    v.y *= scale;
    v.z *= scale;
    v.w *= scale;
    po[i] = v;
}

// ---------------------------------------------------------------- pointer scatter
__global__ __launch_bounds__(512) void k_scatter(float* __restrict__ out, const f16* __restrict__ ah,
                                                 const float* __restrict__ pg, const int* __restrict__ x) {
    int r = blockIdx.x, s = threadIdx.x;
    int b = r / 270;
    int xv = x[(long)b * S_ + s];
    if (xv == 0) return;
    float a = (float)ah[(long)r * S_ + s];
    if (a == 0.f) return;
    atomicAdd(out + (long)r * V_ + xv, (1.f - pg[r]) * a);
}

// ---------------------------------------------------------------- host
extern "C" void kernel_launch(void* const* d_in, const int* in_sizes, int n_in, void* d_out,
                              int out_size, void* d_ws, size_t ws_size, hipStream_t stream) {
    (void)in_sizes; (void)n_in; (void)out_size; (void)ws_size;
    const int* x = (const int*)d_in[0];
    const float* dec = (const float*)d_in[1];
    const float* enc = (const float*)d_in[2];
    const float* hid = (const float*)d_in[3];
    const int* tea = (const int*)d_in[4];
    const float* emb = (const float*)d_in[6];
    const float* wih = (const float*)d_in[7];
    const float* whh = (const float*)d_in[8];
    const float* bih = (const float*)d_in[9];
    const float* bhh = (const float*)d_in[10];
    const float* wgw = (const float*)d_in[11];
    const float* wgb = (const float*)d_in[12];
    float* out = (float*)d_out;

    char* w = (char*)d_ws;
    size_t off = 0;
    auto alloc = [&](size_t bytes) {
        void* p = w + off;
        off = (off + bytes + 255) & ~(size_t)255;
        return p;
    };
    ull* hbuf = (ull*)alloc(8 * 1536 * 8);          // [chain][parity][768] seq-tagged h
    f16* Wall = (f16*)alloc((size_t)R_ * H_ * 2);
    f16* wih16 = (f16*)alloc((size_t)H3 * H_ * 2);
    f16* wh16 = (f16*)alloc((size_t)H3 * H_ * 2);
    float* giA = (float*)alloc((size_t)R_ * H3 * 4);
    f16* Hhi = (f16*)alloc((size_t)R_ * H_ * 2);
    f16* Hlo = (f16*)alloc((size_t)R_ * H_ * 2);
    f16* emb16 = (f16*)alloc((size_t)V_ * H_ * 2);
    f16* ehi = (f16*)alloc((size_t)B_ * S_ * H_ * 2);
    f16* elo = (f16*)alloc((size_t)B_ * S_ * H_ * 2);
    f16* encT = (f16*)alloc((size_t)B_ * H_ * S_ * 2);
    float* lgH = (float*)alloc((size_t)R_ * S_ * 4);
    f16* ah = (f16*)alloc((size_t)R_ * S_ * 2);
    float* ctx = (float*)alloc((size_t)R_ * H_ * 4);
    float* pg = (float*)alloc(R_ * 4);
    float* psum = (float*)alloc((size_t)VNT * R_ * 4);
    float* rinv = (float*)alloc(R_ * 4);

    const int nH = 8 * 1536 * 2;                    // hbuf as ints
    k_zero<<<(nH + 255) / 256, 256, 0, stream>>>((int*)hbuf, nH);
    k_cast<<<2048, 256, 0, stream>>>(emb, emb16, (long)V_ * H_);
    k_cast<<<512, 256, 0, stream>>>(wih, wih16, (long)H3 * H_);
    k_cast<<<512, 256, 0, stream>>>(whh, wh16, (long)H3 * H_);
    k_build_wall<<<R_, 256, 0, stream>>>(emb, dec, tea, Wall);
    k_build_enc<<<1024, 256, 0, stream>>>(enc, ehi, elo, encT);
    k_init_h<<<24, 256, 0, stream>>>(hid, hbuf);

    // gi = W_all @ w_ih^T + b_ih
    {
        dim3 g(H3 / 128, (R_ + 127) / 128, 1);
        k_gemm<1><<<g, 256, 0, stream>>>(Wall, wih16, giA, bih, R_, H3, H_, 0, 0, 0);
    }
    k_gru<<<8 * CBLK, 256, 0, stream>>>(giA, wh16, bhh, hbuf, Hhi, Hlo);

    // attention logits (merged hi/lo): Hhi*Ehi + Hhi*Elo + Hlo*Ehi
    {
        dim3 g(S_ / 128, 3, 8);
        k_attn3<<<g, 256, 0, stream>>>(Hhi, Hlo, ehi, elo, lgH, 270, S_, H_,
                                       270L * H_, (long)S_ * H_, 270L * S_);
    }
    k_attn_softmax<<<R_, 256, 0, stream>>>(lgH, x, ah);
    {
        dim3 g(H_ / 128, 3, 8);
        k_gemm<0><<<g, 256, 0, stream>>>(ah, encT, ctx, nullptr, 270, H_, S_, 270L * S_, (long)H_ * S_, 270L * H_);
    }
    k_pgen<<<R_, 256, 0, stream>>>(Wall, Hhi, Hlo, ctx, wgw, wgb, pg);

    // vocab: out = exp(Hhi @ emb16^T), row partial sums -> psum (XCD-swizzled grid)
    k_vocab<<<VMT * VNT, 256, 0, stream>>>(Hhi, emb16, out, psum);
    k_redsum<<<(R_ + 255) / 256, 256, 0, stream>>>(psum, rinv, VNT);
    {
        dim3 g((V_ / 4 + 255) / 256, R_, 1);
        k_final<<<g, 256, 0, stream>>>(out, rinv, pg);
    }
    k_scatter<<<R_, 512, 0, stream>>>(out, ah, pg, x);
}

// Round 10
// 1120.740 us; speedup vs baseline: 1.9676x; 1.0278x over previous
//
#include <hip/hip_runtime.h>
#include <hip/hip_bf16.h>

typedef _Float16 f16;
typedef _Float16 f16x8 __attribute__((ext_vector_type(8)));
typedef _Float16 f16x4v __attribute__((ext_vector_type(4)));
typedef _Float16 h2 __attribute__((ext_vector_type(2)));
typedef float f32x4 __attribute__((ext_vector_type(4)));
typedef unsigned ui4v __attribute__((ext_vector_type(4)));
typedef unsigned long long ull;

#define B_ 8
#define S_ 512
#define H_ 768
#define V_ 35004
#define J_ 30
#define K_ 9
#define R_ 2160          // B*J*K rows, row r = b*270 + j*9 + t  (matches out layout)
#define H3 2304
#define VMT 17           // vocab M tiles
#define VNT 274          // vocab N tiles

// ---------------------------------------------------------------- prep kernels

__global__ void k_zero(int* p, int n) {
    int i = blockIdx.x * 256 + threadIdx.x;
    if (i < n) p[i] = 0;
}

__global__ void k_cast(const float* __restrict__ s, f16* __restrict__ d, long n) {
    for (long i = (long)blockIdx.x * 256 + threadIdx.x; i < n; i += (long)gridDim.x * 256)
        d[i] = (f16)s[i];
}

// W_all[r] = (t==0) ? decoder_input[b,j,:] : embed[teacher[b,j,t-1],:]
__global__ void k_build_wall(const float* __restrict__ emb, const float* __restrict__ dec,
                             const int* __restrict__ teacher, f16* __restrict__ Wall) {
    int r = blockIdx.x;
    int b = r / 270, s = r % 270, j = s / 9, t = s % 9;
    const float* src = (t == 0) ? dec + ((long)b * J_ + j) * H_
                                : emb + (long)teacher[((long)b * J_ + j) * K_ + (t - 1)] * H_;
    f16* dst = Wall + (long)r * H_;
    for (int c = threadIdx.x; c < H_; c += 256) dst[c] = (f16)src[c];
}

// h exchange word: {seq:32 | f32 bits:32}; chain-major [chain][parity][768]
__global__ void k_init_h(const float* __restrict__ hidden, ull* __restrict__ hbuf) {
    int i = blockIdx.x * 256 + threadIdx.x;
    if (i < B_ * H_) {
        int b = i / H_, u = i % H_;
        hbuf[(long)b * 1536 + u] = (ull)__float_as_uint(hidden[i]);  // seq 0, parity 0
    }
}

// ---------------------------------------------------------------- shared GEMM helpers
typedef const __attribute__((address_space(1))) unsigned GASU;
typedef __attribute__((address_space(3))) unsigned LASU;
__device__ __forceinline__ void gld16(const f16* g, f16* l) {
    __builtin_amdgcn_global_load_lds((GASU*)g, (LASU*)l, 16, 0, 0);
}

// ---------------------------------------------------------------- f16 MFMA GEMM (m97 structure)
// C[M,N] = A[M,K] @ B[N,K]^T ; MODE 0: store, 1: store + bias[col]
template <int MODE>
__global__ __launch_bounds__(256) void k_gemm(const f16* __restrict__ A, const f16* __restrict__ Bm,
                                              float* __restrict__ C, const float* __restrict__ bias,
                                              int M, int N, int K, long sA, long sB, long sC) {
    A += (long)blockIdx.z * sA;
    Bm += (long)blockIdx.z * sB;
    C += (long)blockIdx.z * sC;
    const int m0 = blockIdx.y * 128, n0 = blockIdx.x * 128;
    __shared__ f16 As[128 * 32];
    __shared__ f16 Bs[128 * 32];
    const int tid = threadIdx.x, lane = tid & 63, wave = tid >> 6;
    const int wm = wave >> 1, wn = wave & 1;
    const int fr = lane & 15, kg = lane >> 4;
    f32x4 acc[4][4] = {};
    const int idxu = wave * 128;
    const int i0 = idxu + lane, i1 = idxu + 64 + lane;
    const int r0 = i0 >> 2, k80 = i0 & 3;
    const int r1 = i1 >> 2, k81 = i1 & 3;
    int ga0 = m0 + r0; if (ga0 >= M) ga0 = M - 1;
    int ga1 = m0 + r1; if (ga1 >= M) ga1 = M - 1;
    int gb0 = n0 + r0; if (gb0 >= N) gb0 = N - 1;
    int gb1 = n0 + r1; if (gb1 >= N) gb1 = N - 1;
    const f16* pa0 = A + (long)ga0 * K + k80 * 8;
    const f16* pa1 = A + (long)ga1 * K + k81 * 8;
    const f16* pb0 = Bm + (long)gb0 * K + k80 * 8;
    const f16* pb1 = Bm + (long)gb1 * K + k81 * 8;
    for (int kt = 0; kt < K; kt += 32) {
        gld16(pa0 + kt, As + idxu * 8);
        gld16(pa1 + kt, As + idxu * 8 + 512);
        gld16(pb0 + kt, Bs + idxu * 8);
        gld16(pb1 + kt, Bs + idxu * 8 + 512);
        __syncthreads();
        f16x8 af[4], bf[4];
#pragma unroll
        for (int m = 0; m < 4; ++m) af[m] = *(const f16x8*)(As + (wm * 64 + m * 16 + fr) * 32 + kg * 8);
#pragma unroll
        for (int n = 0; n < 4; ++n) bf[n] = *(const f16x8*)(Bs + (wn * 64 + n * 16 + fr) * 32 + kg * 8);
#pragma unroll
        for (int m = 0; m < 4; ++m)
#pragma unroll
            for (int n = 0; n < 4; ++n)
                acc[m][n] = __builtin_amdgcn_mfma_f32_16x16x32_f16(af[m], bf[n], acc[m][n], 0, 0, 0);
        __syncthreads();
    }
    const int crow = m0 + wm * 64 + (lane >> 4) * 4;
    const int ccol = n0 + wn * 64 + fr;
#pragma unroll
    for (int n = 0; n < 4; ++n) {
        int col = ccol + n * 16;
        if (col >= N) continue;
        float bv = (MODE == 1) ? bias[col] : 0.f;
#pragma unroll
        for (int m = 0; m < 4; ++m) {
#pragma unroll
            for (int q = 0; q < 4; ++q) {
                int row = crow + m * 16 + q;
                if (row < M) C[(long)row * N + col] = acc[m][n][q] + bv;
            }
        }
    }
}

// ---------------------------------------------------------------- merged hi/lo attention logits
__global__ __launch_bounds__(256) void k_attn3(const f16* __restrict__ Ahi, const f16* __restrict__ Alo,
                                               const f16* __restrict__ Bhi, const f16* __restrict__ Blo,
                                               float* __restrict__ C, int M, int N, int K,
                                               long sA, long sB, long sC) {
    const long za = (long)blockIdx.z * sA, zb = (long)blockIdx.z * sB;
    C += (long)blockIdx.z * sC;
    const int m0 = blockIdx.y * 128, n0 = blockIdx.x * 128;
    __shared__ f16 As[128 * 32];
    __shared__ f16 Bs[128 * 32];
    const int tid = threadIdx.x, lane = tid & 63, wave = tid >> 6;
    const int wm = wave >> 1, wn = wave & 1;
    const int fr = lane & 15, kg = lane >> 4;
    f32x4 acc[4][4] = {};
    const int idxu = wave * 128;
    const int i0 = idxu + lane, i1 = idxu + 64 + lane;
    const int r0 = i0 >> 2, k80 = i0 & 3;
    const int r1 = i1 >> 2, k81 = i1 & 3;
    int ga0 = m0 + r0; if (ga0 >= M) ga0 = M - 1;
    int ga1 = m0 + r1; if (ga1 >= M) ga1 = M - 1;
    int gb0 = n0 + r0; if (gb0 >= N) gb0 = N - 1;
    int gb1 = n0 + r1; if (gb1 >= N) gb1 = N - 1;
    const long oa0 = (long)ga0 * K + k80 * 8, oa1 = (long)ga1 * K + k81 * 8;
    const long ob0 = (long)gb0 * K + k80 * 8, ob1 = (long)gb1 * K + k81 * 8;
    for (int ph = 0; ph < 3; ++ph) {
        const f16* Ap = (ph == 2 ? Alo : Ahi) + za;
        const f16* Bp = (ph == 1 ? Blo : Bhi) + zb;
        for (int kt = 0; kt < K; kt += 32) {
            gld16(Ap + oa0 + kt, As + idxu * 8);
            gld16(Ap + oa1 + kt, As + idxu * 8 + 512);
            gld16(Bp + ob0 + kt, Bs + idxu * 8);
            gld16(Bp + ob1 + kt, Bs + idxu * 8 + 512);
            __syncthreads();
            f16x8 af[4], bf[4];
#pragma unroll
            for (int m = 0; m < 4; ++m) af[m] = *(const f16x8*)(As + (wm * 64 + m * 16 + fr) * 32 + kg * 8);
#pragma unroll
            for (int n = 0; n < 4; ++n) bf[n] = *(const f16x8*)(Bs + (wn * 64 + n * 16 + fr) * 32 + kg * 8);
#pragma unroll
            for (int m = 0; m < 4; ++m)
#pragma unroll
                for (int n = 0; n < 4; ++n)
                    acc[m][n] = __builtin_amdgcn_mfma_f32_16x16x32_f16(af[m], bf[n], acc[m][n], 0, 0, 0);
            __syncthreads();
        }
    }
    const int crow = m0 + wm * 64 + (lane >> 4) * 4;
    const int ccol = n0 + wn * 64 + fr;
#pragma unroll
    for (int n = 0; n < 4; ++n) {
        int col = ccol + n * 16;
        if (col >= N) continue;
#pragma unroll
        for (int m = 0; m < 4; ++m) {
#pragma unroll
            for (int q = 0; q < 4; ++q) {
                int row = crow + m * 16 + q;
                if (row < M) C[(long)row * N + col] = acc[m][n][q];
            }
        }
    }
}

// ---------------------------------------------------------------- vocab GEMM: out=exp(Hhi@emb^T), psum
__global__ __launch_bounds__(256) void k_vocab(const f16* __restrict__ A, const f16* __restrict__ Bm,
                                               float* __restrict__ C, float* __restrict__ psum) {
    const int M = R_, N = V_, K = H_;
    const int nwg = VMT * VNT;
    int lin = blockIdx.x;
    int q8 = nwg / 8, r8 = nwg % 8;
    int xcd = lin & 7, idx = lin >> 3;
    int newlin = (xcd < r8) ? xcd * (q8 + 1) + idx : r8 * (q8 + 1) + (xcd - r8) * q8 + idx;
    int mt = newlin % VMT, nt = newlin / VMT;
    const int m0 = mt * 128, n0 = nt * 128;
    __shared__ f16 As[128 * 32];
    __shared__ f16 Bs[128 * 32];
    __shared__ float rpart[2][128];
    const int tid = threadIdx.x, lane = tid & 63, wave = tid >> 6;
    const int wm = wave >> 1, wn = wave & 1;
    const int fr = lane & 15, kg = lane >> 4;
    f32x4 acc[4][4] = {};
    const int idxu = wave * 128;
    const int i0 = idxu + lane, i1 = idxu + 64 + lane;
    const int r0 = i0 >> 2, k80 = i0 & 3;
    const int r1 = i1 >> 2, k81 = i1 & 3;
    int ga0 = m0 + r0; if (ga0 >= M) ga0 = M - 1;
    int ga1 = m0 + r1; if (ga1 >= M) ga1 = M - 1;
    int gb0 = n0 + r0; if (gb0 >= N) gb0 = N - 1;
    int gb1 = n0 + r1; if (gb1 >= N) gb1 = N - 1;
    const f16* pa0 = A + (long)ga0 * K + k80 * 8;
    const f16* pa1 = A + (long)ga1 * K + k81 * 8;
    const f16* pb0 = Bm + (long)gb0 * K + k80 * 8;
    const f16* pb1 = Bm + (long)gb1 * K + k81 * 8;
    for (int kt = 0; kt < K; kt += 32) {
        gld16(pa0 + kt, As + idxu * 8);
        gld16(pa1 + kt, As + idxu * 8 + 512);
        gld16(pb0 + kt, Bs + idxu * 8);
        gld16(pb1 + kt, Bs + idxu * 8 + 512);
        __syncthreads();
        f16x8 af[4], bf[4];
#pragma unroll
        for (int m = 0; m < 4; ++m) af[m] = *(const f16x8*)(As + (wm * 64 + m * 16 + fr) * 32 + kg * 8);
#pragma unroll
        for (int n = 0; n < 4; ++n) bf[n] = *(const f16x8*)(Bs + (wn * 64 + n * 16 + fr) * 32 + kg * 8);
#pragma unroll
        for (int m = 0; m < 4; ++m)
#pragma unroll
            for (int n = 0; n < 4; ++n)
                acc[m][n] = __builtin_amdgcn_mfma_f32_16x16x32_f16(af[m], bf[n], acc[m][n], 0, 0, 0);
        __syncthreads();
    }
    const int crow = m0 + wm * 64 + (lane >> 4) * 4;
    const int ccol = n0 + wn * 64 + fr;
    float rs[4][4];
#pragma unroll
    for (int m = 0; m < 4; ++m)
#pragma unroll
        for (int q = 0; q < 4; ++q) rs[m][q] = 0.f;
#pragma unroll
    for (int n = 0; n < 4; ++n) {
        int col = ccol + n * 16;
        if (col >= N) continue;
#pragma unroll
        for (int m = 0; m < 4; ++m) {
#pragma unroll
            for (int q = 0; q < 4; ++q) {
                int row = crow + m * 16 + q;
                if (row < M) {
                    float e = __expf(acc[m][n][q]);
                    C[(long)row * N + col] = e;
                    rs[m][q] += e;
                }
            }
        }
    }
#pragma unroll
    for (int m = 0; m < 4; ++m)
#pragma unroll
        for (int q = 0; q < 4; ++q) {
            float v = rs[m][q];
            v += __shfl_xor(v, 1);
            v += __shfl_xor(v, 2);
            v += __shfl_xor(v, 4);
            v += __shfl_xor(v, 8);
            rs[m][q] = v;
        }
    if ((lane & 15) == 0) {
#pragma unroll
        for (int m = 0; m < 4; ++m)
#pragma unroll
            for (int q = 0; q < 4; ++q)
                rpart[wn][wm * 64 + (lane >> 4) * 4 + m * 16 + q] = rs[m][q];
    }
    __syncthreads();
    if (tid < 128) {
        int row = m0 + tid;
        if (row < M) psum[(long)nt * M + row] = rpart[0][tid] + rpart[1][tid];
    }
}

// ---------------------------------------------------------------- GRU recurrence + hidden preps
// Blocks 0..191: 8 chains x 24 blocks x 32 units (f16 weights in 144 VGPRs,
// staged from f32 whh). Per-WAVE decoupled h exchange: wave w polls/stages only
// its own 192 words; finisher lanes poll their own hold-word; gi prefetched one
// step ahead. Block-level read-all-before-write is preserved via barrier B, so
// the 1-step spread bound / parity double-buffer protocol (R5-proven) holds.
// Blocks 192..255: run on the otherwise-idle 64 CUs, doing emb16 cast + enc
// hi/lo/transpose builds (consumed only by later kernels).
__device__ __forceinline__ float fd2(unsigned hv, unsigned wv, float acc) {
#if __has_builtin(__builtin_amdgcn_fdot2)
    return __builtin_amdgcn_fdot2(__builtin_bit_cast(h2, hv), __builtin_bit_cast(h2, wv), acc, false);
#else
    h2 a = __builtin_bit_cast(h2, hv), b = __builtin_bit_cast(h2, wv);
    return acc + (float)a.x * (float)b.x + (float)a.y * (float)b.y;
#endif
}

__global__ __launch_bounds__(256, 1) void k_gru(const float* __restrict__ gi,
                                                const float* __restrict__ whh,
                                                const float* __restrict__ bhh,
                                                ull* hbuf,
                                                f16* __restrict__ Hhi, f16* __restrict__ Hlo,
                                                const float* __restrict__ emb, f16* __restrict__ emb16,
                                                const float* __restrict__ enc, f16* __restrict__ ehi,
                                                f16* __restrict__ elo, f16* __restrict__ encT) {
    __shared__ ui4v wsvu[9216];               // [g][k8][u]: ((g*96+k8)*32+u), 147456 B
    __shared__ __align__(16) f16 hsf[768];
    __shared__ float part[2][8][32][3];
    const int tid = threadIdx.x;
    if (blockIdx.x >= 192) {
        // ---------- hidden prep on idle CUs ----------
        const long pt = (long)(blockIdx.x - 192) * 256 + tid;   // 0..16383
        const long n4 = (long)V_ * H_ / 4;
        for (long i = pt; i < n4; i += 64 * 256) {
            f32x4 v = ((const f32x4*)emb)[i];
            f16x4v r = {(f16)v.x, (f16)v.y, (f16)v.z, (f16)v.w};
            ((f16x4v*)emb16)[i] = r;
        }
        const long n4e = (long)B_ * S_ * H_ / 4;
        for (long i = pt; i < n4e; i += 64 * 256) {
            f32x4 v = ((const f32x4*)enc)[i];
            long e0 = i * 4;
            int h = (int)(e0 % H_);
            long bs = e0 / H_;
            int ss = (int)(bs % S_), bb = (int)(bs / S_);
            f16 h0 = (f16)v.x, h1 = (f16)v.y, h2v = (f16)v.z, h3 = (f16)v.w;
            f16x4v hv = {h0, h1, h2v, h3};
            ((f16x4v*)ehi)[i] = hv;
            f16x4v lv = {(f16)(v.x - (float)h0), (f16)(v.y - (float)h1),
                         (f16)(v.z - (float)h2v), (f16)(v.w - (float)h3)};
            ((f16x4v*)elo)[i] = lv;
            f16* tp = encT + ((long)bb * H_ + h) * S_ + ss;
            tp[0] = h0;
            tp[S_] = h1;
            tp[2L * S_] = h2v;
            tp[3L * S_] = h3;
        }
        return;
    }
    // ---------- recurrence ----------
    const int chain = blockIdx.x / 24;
    const int blk = blockIdx.x % 24;
    const int u0 = blk * 32;
    for (int idx = tid; idx < 9216; idx += 256) {
        int uu = idx & 31, k8 = (idx >> 5) % 96, g = idx / (96 * 32);
        const float* src = whh + (long)(g * H_ + u0 + uu) * H_ + k8 * 8;
        f32x4 a = *(const f32x4*)src;
        f32x4 b2 = *(const f32x4*)(src + 4);
        f16x8 pk = {(f16)a.x, (f16)a.y, (f16)a.z, (f16)a.w,
                    (f16)b2.x, (f16)b2.y, (f16)b2.z, (f16)b2.w};
        wsvu[idx] = __builtin_bit_cast(ui4v, pk);
    }
    float b_r = 0.f, b_z = 0.f, b_n = 0.f;
    if (tid < 32) {
        int c = u0 + tid;
        b_r = bhh[c];
        b_z = bhh[H_ + c];
        b_n = bhh[2 * H_ + c];
    }
    __syncthreads();
    const int u = tid & 31, q = tid >> 5, lane = tid & 63;
    const int pw = (tid >> 6) * 192 + lane;   // this wave's h-word base
    ui4v wreg[3][12];
#pragma unroll
    for (int g = 0; g < 3; ++g)
#pragma unroll
        for (int i = 0; i < 12; ++i)
            wreg[g][i] = wsvu[(g * 96 + q * 12 + i) * 32 + u];
    ull* base = hbuf + (long)chain * 1536;
    const bool fin = (tid < 32);
    float g0 = 0.f, g1 = 0.f, g2v = 0.f;
    if (fin) {
        const float* gp = gi + (long)chain * 270 * H3;
        int c = u0 + tid;
        g0 = gp[c];
        g1 = gp[H_ + c];
        g2v = gp[2 * H_ + c];
    }
    for (int s = 0; s < 270; ++s) {
        const ull* rb = base + (s & 1) * 768;
        ull* wb = base + ((s + 1) & 1) * 768;
        const unsigned want = (unsigned)s;
        ull v0, v1, v2, vh = 0;
        for (;;) {
            v0 = __hip_atomic_load(rb + pw, __ATOMIC_RELAXED, __HIP_MEMORY_SCOPE_AGENT);
            v1 = __hip_atomic_load(rb + pw + 64, __ATOMIC_RELAXED, __HIP_MEMORY_SCOPE_AGENT);
            v2 = __hip_atomic_load(rb + pw + 128, __ATOMIC_RELAXED, __HIP_MEMORY_SCOPE_AGENT);
            bool ok = ((unsigned)(v0 >> 32) == want) & ((unsigned)(v1 >> 32) == want) &
                      ((unsigned)(v2 >> 32) == want);
            if (fin) {
                vh = __hip_atomic_load(rb + u0 + tid, __ATOMIC_RELAXED, __HIP_MEMORY_SCOPE_AGENT);
                ok &= ((unsigned)(vh >> 32) == want);
            }
            if (ok) break;
        }
        hsf[pw] = (f16)__uint_as_float((unsigned)v0);
        hsf[pw + 64] = (f16)__uint_as_float((unsigned)v1);
        hsf[pw + 128] = (f16)__uint_as_float((unsigned)v2);
        __builtin_amdgcn_wave_barrier();
        float ar = 0.f, az = 0.f, an = 0.f;
#pragma unroll
        for (int i = 0; i < 12; ++i) {
            ui4v hv = *(const ui4v*)(&hsf[(q * 12 + i) * 8]);
            ui4v wr = wreg[0][i], wz = wreg[1][i], wn = wreg[2][i];
            ar = fd2(hv.x, wr.x, ar); ar = fd2(hv.y, wr.y, ar);
            ar = fd2(hv.z, wr.z, ar); ar = fd2(hv.w, wr.w, ar);
            az = fd2(hv.x, wz.x, az); az = fd2(hv.y, wz.y, az);
            az = fd2(hv.z, wz.z, az); az = fd2(hv.w, wz.w, az);
            an = fd2(hv.x, wn.x, an); an = fd2(hv.y, wn.y, an);
            an = fd2(hv.z, wn.z, an); an = fd2(hv.w, wn.w, an);
        }
        const int par = s & 1;
        part[par][q][u][0] = ar;
        part[par][q][u][1] = az;
        part[par][q][u][2] = an;
        __syncthreads();                       // B: partials ready (block-wide)
        if (fin) {
            float gr = b_r, gz = b_z, gn = b_n;
#pragma unroll
            for (int qq = 0; qq < 8; ++qq) {
                gr += part[par][qq][tid][0];
                gz += part[par][qq][tid][1];
                gn += part[par][qq][tid][2];
            }
            float hold = __uint_as_float((unsigned)vh);
            float rg = 1.f / (1.f + expf(-(g0 + gr)));
            float zg = 1.f / (1.f + expf(-(g1 + gz)));
            float ng = tanhf(g2v + rg * gn);
            float hnew = (1.f - zg) * ng + zg * hold;
            int c = u0 + tid;
            ull wvv = ((ull)(unsigned)(s + 1) << 32) | (ull)__float_as_uint(hnew);
            __hip_atomic_store(wb + c, wvv, __ATOMIC_RELAXED, __HIP_MEMORY_SCOPE_AGENT);
            long row = (long)chain * 270 + s;
            f16 h16 = (f16)hnew;
            Hhi[row * H_ + c] = h16;
            Hlo[row * H_ + c] = (f16)(hnew - (float)h16);
            if (s < 269) {   // prefetch next step's gi (latency hidden behind next poll)
                const float* gp = gi + ((long)chain * 270 + s + 1) * H3;
                g0 = gp[c];
                g1 = gp[H_ + c];
                g2v = gp[2 * H_ + c];
            }
        }
    }
}

// ---------------------------------------------------------------- attention softmax
__global__ __launch_bounds__(256) void k_attn_softmax(const float* __restrict__ lg,
                                                      const int* __restrict__ x, f16* __restrict__ ah) {
    __shared__ float red[256];
    int r = blockIdx.x, tid = threadIdx.x;
    int b = r / 270;
    const float* lr = lg + (long)r * S_;
    const int* xb = x + (long)b * S_;
    float v0 = lr[tid];
    if (xb[tid] == 0) v0 = -1e9f;
    float v1 = lr[tid + 256];
    if (xb[tid + 256] == 0) v1 = -1e9f;
    red[tid] = fmaxf(v0, v1);
    __syncthreads();
    for (int o = 128; o > 0; o >>= 1) {
        if (tid < o) red[tid] = fmaxf(red[tid], red[tid + o]);
        __syncthreads();
    }
    float m = red[0];
    __syncthreads();
    float e0 = __expf(v0 - m), e1 = __expf(v1 - m);
    red[tid] = e0 + e1;
    __syncthreads();
    for (int o = 128; o > 0; o >>= 1) {
        if (tid < o) red[tid] += red[tid + o];
        __syncthreads();
    }
    float inv = 1.f / red[0];
    ah[(long)r * S_ + tid] = (f16)(e0 * inv);
    ah[(long)r * S_ + tid + 256] = (f16)(e1 * inv);
}

// ---------------------------------------------------------------- p_gen
__global__ __launch_bounds__(256) void k_pgen(const f16* __restrict__ Wall, const f16* __restrict__ Hhi,
                                              const f16* __restrict__ Hlo, const float* __restrict__ ctx,
                                              const float* __restrict__ wg, const float* __restrict__ wgb,
                                              float* __restrict__ pg) {
    __shared__ float red[256];
    int r = blockIdx.x, tid = threadIdx.x;
    float a = 0.f;
    for (int i = tid; i < H_; i += 256) {
        a += (float)Wall[(long)r * H_ + i] * wg[i];
        a += ((float)Hhi[(long)r * H_ + i] + (float)Hlo[(long)r * H_ + i]) * wg[H_ + i];
        a += ctx[(long)r * H_ + i] * wg[2 * H_ + i];
    }
    red[tid] = a;
    __syncthreads();
    for (int o = 128; o > 0; o >>= 1) {
        if (tid < o) red[tid] += red[tid + o];
        __syncthreads();
    }
    if (tid == 0) pg[r] = 1.f / (1.f + expf(-(red[0] + wgb[0])));
}

// ---------------------------------------------------------------- rowsum reduce: rinv = 1/sum_b psum[b][r]
__global__ void k_redsum(const float* __restrict__ psum, float* __restrict__ rinv, int nb) {
    int r = blockIdx.x * 256 + threadIdx.x;
    if (r >= R_) return;
    float s = 0.f;
    for (int b = 0; b < nb; ++b) s += psum[(long)b * R_ + r];
    rinv[r] = 1.f / s;
}

// ---------------------------------------------------------------- finalize: out = pg * exp * rinv (in place)
__global__ __launch_bounds__(256) void k_final(float* __restrict__ out, const float* __restrict__ rinv,
                                               const float* __restrict__ pg) {
    int r = blockIdx.y;
    int i = blockIdx.x * 256 + threadIdx.x;
    if (i >= V_ / 4) return;
    float scale = pg[r] * rinv[r];
    f32x4* po = (f32x4*)(out + (long)r * V_);
    f32x4 v = po[i];
    v.x *= scale;
    v.y *= scale;
    v.z *= scale;
    v.w *= scale;
    po[i] = v;
}

// ---------------------------------------------------------------- pointer scatter
__global__ __launch_bounds__(512) void k_scatter(float* __restrict__ out, const f16* __restrict__ ah,
                                                 const float* __restrict__ pg, const int* __restrict__ x) {
    int r = blockIdx.x, s = threadIdx.x;
    int b = r / 270;
    int xv = x[(long)b * S_ + s];
    if (xv == 0) return;
    float a = (float)ah[(long)r * S_ + s];
    if (a == 0.f) return;
    atomicAdd(out + (long)r * V_ + xv, (1.f - pg[r]) * a);
}

// ---------------------------------------------------------------- host
extern "C" void kernel_launch(void* const* d_in, const int* in_sizes, int n_in, void* d_out,
                              int out_size, void* d_ws, size_t ws_size, hipStream_t stream) {
    (void)in_sizes; (void)n_in; (void)out_size; (void)ws_size;
    const int* x = (const int*)d_in[0];
    const float* dec = (const float*)d_in[1];
    const float* enc = (const float*)d_in[2];
    const float* hid = (const float*)d_in[3];
    const int* tea = (const int*)d_in[4];
    const float* emb = (const float*)d_in[6];
    const float* wih = (const float*)d_in[7];
    const float* whh = (const float*)d_in[8];
    const float* bih = (const float*)d_in[9];
    const float* bhh = (const float*)d_in[10];
    const float* wgw = (const float*)d_in[11];
    const float* wgb = (const float*)d_in[12];
    float* out = (float*)d_out;

    char* w = (char*)d_ws;
    size_t off = 0;
    auto alloc = [&](size_t bytes) {
        void* p = w + off;
        off = (off + bytes + 255) & ~(size_t)255;
        return p;
    };
    ull* hbuf = (ull*)alloc(8 * 1536 * 8);          // [chain][parity][768] seq-tagged h
    f16* Wall = (f16*)alloc((size_t)R_ * H_ * 2);
    f16* wih16 = (f16*)alloc((size_t)H3 * H_ * 2);
    float* giA = (float*)alloc((size_t)R_ * H3 * 4);
    f16* Hhi = (f16*)alloc((size_t)R_ * H_ * 2);
    f16* Hlo = (f16*)alloc((size_t)R_ * H_ * 2);
    f16* emb16 = (f16*)alloc((size_t)V_ * H_ * 2);
    f16* ehi = (f16*)alloc((size_t)B_ * S_ * H_ * 2);
    f16* elo = (f16*)alloc((size_t)B_ * S_ * H_ * 2);
    f16* encT = (f16*)alloc((size_t)B_ * H_ * S_ * 2);
    float* lgH = (float*)alloc((size_t)R_ * S_ * 4);
    f16* ah = (f16*)alloc((size_t)R_ * S_ * 2);
    float* ctx = (float*)alloc((size_t)R_ * H_ * 4);
    float* pg = (float*)alloc(R_ * 4);
    float* psum = (float*)alloc((size_t)VNT * R_ * 4);
    float* rinv = (float*)alloc(R_ * 4);

    const int nH = 8 * 1536 * 2;                    // hbuf as ints
    k_zero<<<(nH + 255) / 256, 256, 0, stream>>>((int*)hbuf, nH);
    k_cast<<<512, 256, 0, stream>>>(wih, wih16, (long)H3 * H_);
    k_build_wall<<<R_, 256, 0, stream>>>(emb, dec, tea, Wall);
    k_init_h<<<24, 256, 0, stream>>>(hid, hbuf);

    // gi = W_all @ w_ih^T + b_ih
    {
        dim3 g(H3 / 128, (R_ + 127) / 128, 1);
        k_gemm<1><<<g, 256, 0, stream>>>(Wall, wih16, giA, bih, R_, H3, H_, 0, 0, 0);
    }
    // recurrence (blocks 0-191) + hidden preps on idle CUs (blocks 192-255)
    k_gru<<<256, 256, 0, stream>>>(giA, whh, bhh, hbuf, Hhi, Hlo,
                                   emb, emb16, enc, ehi, elo, encT);

    // attention logits (merged hi/lo): Hhi*Ehi + Hhi*Elo + Hlo*Ehi
    {
        dim3 g(S_ / 128, 3, 8);
        k_attn3<<<g, 256, 0, stream>>>(Hhi, Hlo, ehi, elo, lgH, 270, S_, H_,
                                       270L * H_, (long)S_ * H_, 270L * S_);
    }
    k_attn_softmax<<<R_, 256, 0, stream>>>(lgH, x, ah);
    {
        dim3 g(H_ / 128, 3, 8);
        k_gemm<0><<<g, 256, 0, stream>>>(ah, encT, ctx, nullptr, 270, H_, S_, 270L * S_, (long)H_ * S_, 270L * H_);
    }
    k_pgen<<<R_, 256, 0, stream>>>(Wall, Hhi, Hlo, ctx, wgw, wgb, pg);

    // vocab: out = exp(Hhi @ emb16^T), row partial sums -> psum (XCD-swizzled grid)
    k_vocab<<<VMT * VNT, 256, 0, stream>>>(Hhi, emb16, out, psum);
    k_redsum<<<(R_ + 255) / 256, 256, 0, stream>>>(psum, rinv, VNT);
    {
        dim3 g((V_ / 4 + 255) / 256, R_, 1);
        k_final<<<g, 256, 0, stream>>>(out, rinv, pg);
    }
    k_scatter<<<R_, 512, 0, stream>>>(out, ah, pg, x);
}